// Round 3
// baseline (1010.157 us; speedup 1.0000x reference)
//
#include <hip/hip_runtime.h>
#include <math.h>

#define BATCH 8
#define CIN 512
#define CO 256
#define HW 4096
#define KT 32
#define NCHUNK 128  // pass-1 y-chunks of 32

typedef unsigned short ushort_t;
typedef unsigned int uint_t;
typedef __bf16 v8bf __attribute__((ext_vector_type(8)));
typedef _Float16 v8h __attribute__((ext_vector_type(8)));
typedef _Float16 v4h __attribute__((ext_vector_type(4)));
typedef float v4f __attribute__((ext_vector_type(4)));

__device__ __forceinline__ ushort_t f2bf(float f) {
  uint_t u = __float_as_uint(f);
  u += 0x7FFFu + ((u >> 16) & 1u);
  return (ushort_t)(u >> 16);
}
__device__ __forceinline__ float bf2f(ushort_t h) {
  return __uint_as_float(((uint_t)h) << 16);
}
__device__ __forceinline__ v4f mfma16(v8bf a, v8bf b, v4f c) {
  return __builtin_amdgcn_mfma_f32_16x16x32_bf16(a, b, c, 0, 0, 0);
}
__device__ __forceinline__ v4f mfma16h(v8h a, v8h b, v4f c) {
  return __builtin_amdgcn_mfma_f32_16x16x32_f16(a, b, c, 0, 0, 0);
}
__device__ __forceinline__ v8bf lds_frag(const unsigned char* base, int row, int cb, int pitch) {
  uint4 v = *(const uint4*)(base + (size_t)row * pitch + (((cb) ^ (row & 7)) << 4));
  return __builtin_bit_cast(v8bf, v);
}
__device__ __forceinline__ v8h lds_frag_h(const unsigned char* base, int row, int cb, int pitch) {
  uint4 v = *(const uint4*)(base + (size_t)row * pitch + (((cb) ^ (row & 7)) << 4));
  return __builtin_bit_cast(v8h, v);
}
__device__ __forceinline__ void gll16(const void* g, void* l) {
  __builtin_amdgcn_global_load_lds(
      (const __attribute__((address_space(1))) unsigned int*)g,
      (__attribute__((address_space(3))) unsigned int*)l, 16, 0, 0);
}

// ===========================================================================
// Prep kernels
// ===========================================================================

// proj = W@x + bias (fp32 VALU), output split-bf16 transposed: proj_t[b][x][c]
__global__ __launch_bounds__(256) void k_proj_split(
    const float* __restrict__ x, const float* __restrict__ W,
    const float* __restrict__ bias,
    ushort_t* __restrict__ proj_hi, ushort_t* __restrict__ proj_lo) {
  __shared__ float As[KT][68];
  __shared__ float Bs[KT][68];
  const int i0 = blockIdx.x * 64;
  const int o0 = blockIdx.y * 64;
  const int b  = blockIdx.z;
  const int t  = threadIdx.x;
  const int tx = t & 15, ty = t >> 4;
  const float* xb = x + (size_t)b * CIN * HW;
  float acc[4][4] = {};
  for (int c0 = 0; c0 < CIN; c0 += KT) {
#pragma unroll
    for (int l = 0; l < 8; ++l) {
      int idx = t + l * 256;
      int o = idx >> 5;
      int c = idx & 31;
      As[c][o] = W[(size_t)(o0 + o) * CIN + c0 + c];
    }
#pragma unroll
    for (int l = 0; l < 2; ++l) {
      int idx4 = t + l * 256;
      int c = idx4 >> 4;
      int i4 = idx4 & 15;
      *(float4*)&Bs[c][i4 * 4] =
          *(const float4*)&xb[(size_t)(c0 + c) * HW + i0 + i4 * 4];
    }
    __syncthreads();
#pragma unroll
    for (int c = 0; c < KT; ++c) {
      float4 a  = *(const float4*)&As[c][tx * 4];
      float4 bv = *(const float4*)&Bs[c][ty * 4];
      float av[4] = {a.x, a.y, a.z, a.w};
      float bb[4] = {bv.x, bv.y, bv.z, bv.w};
#pragma unroll
      for (int u = 0; u < 4; ++u)
#pragma unroll
        for (int v = 0; v < 4; ++v) acc[u][v] += av[u] * bb[v];
    }
    __syncthreads();
  }
  float bs[4];
#pragma unroll
  for (int u = 0; u < 4; ++u) bs[u] = bias[o0 + tx * 4 + u];
#pragma unroll
  for (int v = 0; v < 4; ++v) {
    int xx = i0 + ty * 4 + v;
    ushort4 hi, lo;
    float z0 = acc[0][v] + bs[0];
    float z1 = acc[1][v] + bs[1];
    float z2 = acc[2][v] + bs[2];
    float z3 = acc[3][v] + bs[3];
    hi.x = f2bf(z0); hi.y = f2bf(z1); hi.z = f2bf(z2); hi.w = f2bf(z3);
    lo.x = f2bf(z0 - bf2f(hi.x)); lo.y = f2bf(z1 - bf2f(hi.y));
    lo.z = f2bf(z2 - bf2f(hi.z)); lo.w = f2bf(z3 - bf2f(hi.w));
    size_t off = ((size_t)b * HW + xx) * CO + o0 + tx * 4;
    *(ushort4*)&proj_hi[off] = hi;
    *(ushort4*)&proj_lo[off] = lo;
  }
}

// pem [b][c][y] fp32 -> pem_t[b][y][c] hi/lo bf16 (transposed)  and
// pem_aux[b][c][y]: f16 when aux_f16!=0 (new path), bf16 otherwise (tier-2)
__global__ __launch_bounds__(256) void k_tr_pem(
    const float* __restrict__ pem,
    ushort_t* __restrict__ pem_t_hi, ushort_t* __restrict__ pem_t_lo,
    ushort_t* __restrict__ pem_aux, int aux_f16) {
  __shared__ float T[64][65];
  const int y0 = blockIdx.x * 64;
  const int c0 = blockIdx.y * 64;
  const int b  = blockIdx.z;
  const int t  = threadIdx.x;
  const int cl = t >> 4;
  const int y4 = (t & 15) * 4;
#pragma unroll
  for (int r = 0; r < 4; ++r) {
    int c = c0 + r * 16 + cl;
    size_t off = ((size_t)b * CO + c) * HW + y0 + y4;
    float4 v = *(const float4*)&pem[off];
    ushort4 h;
    if (aux_f16) {
      h.x = __builtin_bit_cast(ushort_t, (_Float16)v.x);
      h.y = __builtin_bit_cast(ushort_t, (_Float16)v.y);
      h.z = __builtin_bit_cast(ushort_t, (_Float16)v.z);
      h.w = __builtin_bit_cast(ushort_t, (_Float16)v.w);
    } else {
      h.x = f2bf(v.x); h.y = f2bf(v.y); h.z = f2bf(v.z); h.w = f2bf(v.w);
    }
    *(ushort4*)&pem_aux[off] = h;
    T[r * 16 + cl][y4 + 0] = v.x;
    T[r * 16 + cl][y4 + 1] = v.y;
    T[r * 16 + cl][y4 + 2] = v.z;
    T[r * 16 + cl][y4 + 3] = v.w;
  }
  __syncthreads();
  const int yl = t >> 2;
  const int cq = (t & 3) * 16;
  size_t rowoff = ((size_t)b * HW + y0 + yl) * CO + c0 + cq;
#pragma unroll
  for (int j4 = 0; j4 < 4; ++j4) {
    ushort4 h, l;
    float f0 = T[cq + j4 * 4 + 0][yl];
    float f1 = T[cq + j4 * 4 + 1][yl];
    float f2 = T[cq + j4 * 4 + 2][yl];
    float f3 = T[cq + j4 * 4 + 3][yl];
    h.x = f2bf(f0); h.y = f2bf(f1); h.z = f2bf(f2); h.w = f2bf(f3);
    l.x = f2bf(f0 - bf2f(h.x)); l.y = f2bf(f1 - bf2f(h.y));
    l.z = f2bf(f2 - bf2f(h.z)); l.w = f2bf(f3 - bf2f(h.w));
    *(ushort4*)&pem_t_hi[rowoff + j4 * 4] = h;
    *(ushort4*)&pem_t_lo[rowoff + j4 * 4] = l;
  }
}

// ===========================================================================
// Pass 1: stats + E' materialization.
// Block: 256 thr (4 waves), x-tile 128 (wave owns 32 x, A in registers).
// Loops y in chunks of 32 (pem_t staged via global_load_lds, dbuf, swizzled).
// Writes E'[bl][y][x] = exp(S - m_run) fp16, m_snap[b][t][x], Mx, Dinv.
// ===========================================================================
__global__ __launch_bounds__(256) void k_pass1(
    const ushort_t* __restrict__ proj_hi, const ushort_t* __restrict__ proj_lo,
    const ushort_t* __restrict__ pem_t_hi, const ushort_t* __restrict__ pem_t_lo,
    _Float16* __restrict__ Ep, float* __restrict__ m_snap,
    float* __restrict__ Mx, float* __restrict__ Dinv, int b_base) {
  __shared__ __align__(16) unsigned char pbuf[2][2][32 * 512];
  const int bl = blockIdx.x;
  const int b  = b_base + bl;
  const int x0 = blockIdx.y * 128;
  const int t  = threadIdx.x;
  const int lane = t & 63, wave = t >> 6;
  const int xw = x0 + wave * 32;

  // ---- A fragments resident in registers (proj hi/lo, K=256) ----
  v8bf Ah[2][8], Al[2][8];
#pragma unroll
  for (int xf = 0; xf < 2; ++xf) {
    const size_t ro =
        ((size_t)b * HW + xw + xf * 16 + (lane & 15)) * CO + (lane >> 4) * 8;
#pragma unroll
    for (int st = 0; st < 8; ++st) {
      Ah[xf][st] = __builtin_bit_cast(v8bf, *(const uint4*)&proj_hi[ro + st * 32]);
      Al[xf][st] = __builtin_bit_cast(v8bf, *(const uint4*)&proj_lo[ro + st * 32]);
    }
  }

  float m[2][4], d[2][4];
#pragma unroll
  for (int xf = 0; xf < 2; ++xf)
#pragma unroll
    for (int r = 0; r < 4; ++r) { m[xf][r] = -3.0e38f; d[xf][r] = 0.f; }

  auto stage = [&](int bufi, int yc0) {
#pragma unroll
    for (int i = 0; i < 4; ++i) {
      int G = i * 256 + t;
      int r = G >> 5, sl = G & 31;
      size_t so = ((size_t)b * HW + yc0 + r) * CO + ((sl ^ (r & 7)) << 3);
      unsigned lb = (unsigned)((i * 256 + wave * 64) << 4);
      gll16(&pem_t_hi[so], &pbuf[bufi][0][lb]);
      gll16(&pem_t_lo[so], &pbuf[bufi][1][lb]);
    }
  };

  stage(0, 0);
  __syncthreads();

  for (int tt = 0; tt < NCHUNK; ++tt) {
    if (tt + 1 < NCHUNK) stage((tt + 1) & 1, (tt + 1) * 32);

    const unsigned char* bh_p = pbuf[tt & 1][0];
    const unsigned char* bl_p = pbuf[tt & 1][1];
    v4f acc[2][2];
#pragma unroll
    for (int xf = 0; xf < 2; ++xf)
#pragma unroll
      for (int yc = 0; yc < 2; ++yc) acc[xf][yc] = (v4f){0.f, 0.f, 0.f, 0.f};

#pragma unroll
    for (int st = 0; st < 8; ++st) {
#pragma unroll
      for (int yc = 0; yc < 2; ++yc) {
        int row = yc * 16 + (lane & 15);
        int cb  = st * 4 + (lane >> 4);
        v8bf bh = lds_frag(bh_p, row, cb, 512);
        v8bf bv = lds_frag(bl_p, row, cb, 512);
        acc[0][yc] = mfma16(Ah[0][st], bh, acc[0][yc]);
        acc[1][yc] = mfma16(Ah[1][st], bh, acc[1][yc]);
        acc[0][yc] = mfma16(Al[0][st], bh, acc[0][yc]);
        acc[1][yc] = mfma16(Al[1][st], bh, acc[1][yc]);
        acc[0][yc] = mfma16(Ah[0][st], bv, acc[0][yc]);
        acc[1][yc] = mfma16(Ah[1][st], bv, acc[1][yc]);
      }
    }

    // ---- online stats + E' write ----
#pragma unroll
    for (int xf = 0; xf < 2; ++xf) {
      float rm[4];
#pragma unroll
      for (int r = 0; r < 4; ++r) rm[r] = fmaxf(acc[xf][0][r], acc[xf][1][r]);
#pragma unroll
      for (int r = 0; r < 4; ++r) {
        rm[r] = fmaxf(rm[r], __shfl_xor(rm[r], 1));
        rm[r] = fmaxf(rm[r], __shfl_xor(rm[r], 2));
        rm[r] = fmaxf(rm[r], __shfl_xor(rm[r], 4));
        rm[r] = fmaxf(rm[r], __shfl_xor(rm[r], 8));
      }
      v4h p0, p1;
#pragma unroll
      for (int r = 0; r < 4; ++r) {
        float mn = fmaxf(m[xf][r], rm[r]);
        d[xf][r] *= __expf(m[xf][r] - mn);
        m[xf][r] = mn;
        float e0 = __expf(acc[xf][0][r] - mn);
        float e1 = __expf(acc[xf][1][r] - mn);
        d[xf][r] += e0 + e1;
        p0[r] = (_Float16)e0;
        p1[r] = (_Float16)e1;
      }
      {
        size_t xcol = (size_t)(xw + xf * 16 + (lane >> 4) * 4);
        size_t rb = ((size_t)bl * HW + tt * 32 + (lane & 15)) * HW + xcol;
        *(uint2*)&Ep[rb] = __builtin_bit_cast(uint2, p0);
        *(uint2*)&Ep[rb + (size_t)16 * HW] = __builtin_bit_cast(uint2, p1);
      }
#pragma unroll
      for (int r = 0; r < 4; ++r)
        if ((lane & 15) == r)
          m_snap[((size_t)b * NCHUNK + tt) * HW + xw + xf * 16 + (lane >> 4) * 4 + r] =
              m[xf][r];
    }
    __syncthreads();
  }

  // ---- final M / Dinv ----
#pragma unroll
  for (int xf = 0; xf < 2; ++xf)
#pragma unroll
    for (int r = 0; r < 4; ++r) {
      float dv = d[xf][r];
      dv += __shfl_xor(dv, 1);
      dv += __shfl_xor(dv, 2);
      dv += __shfl_xor(dv, 4);
      dv += __shfl_xor(dv, 8);
      if ((lane & 15) == r) {
        int xr = xw + xf * 16 + (lane >> 4) * 4 + r;
        Mx[(size_t)b * HW + xr] = m[xf][r];
        Dinv[(size_t)b * HW + xr] = 1.0f / dv;
      }
    }
}

// s[b][t][x] = exp(m_snap[b][t][x] - M[b][x]) * Dinv[b][x]   (f16)
__global__ __launch_bounds__(256) void k_sfin(
    const float* __restrict__ m_snap, const float* __restrict__ Mx,
    const float* __restrict__ Dinv, _Float16* __restrict__ s_h) {
  const int b  = blockIdx.x >> 7;
  const int tt = blockIdx.x & 127;
  const float* ms = m_snap + ((size_t)b * NCHUNK + tt) * HW;
  _Float16* so = s_h + ((size_t)b * NCHUNK + tt) * HW;
  const float* Mb = Mx + (size_t)b * HW;
  const float* Db = Dinv + (size_t)b * HW;
  for (int xx = threadIdx.x; xx < HW; xx += 256)
    so[xx] = (_Float16)(__expf(ms[xx] - Mb[xx]) * Db[xx]);
}

// ===========================================================================
// Pass 2: out[b,k,y] = sum_x pem[k,x] * s[x]*E'[x? -> stored [y][x]] , f16 MFMA
// Block: 256 thr (4 waves), y-tile 64, x loop in 64-chunks, dbuf staging.
// ===========================================================================
__global__ __launch_bounds__(256, 2) void k_pass2(
    const _Float16* __restrict__ Ep, const _Float16* __restrict__ pem_h,
    const _Float16* __restrict__ s_h, float* __restrict__ out, int b_base) {
  __shared__ __align__(16) unsigned char pml[2][CO * 128];
  __shared__ __align__(16) unsigned char el[2][64 * 128];
  const int bl = blockIdx.x;
  const int b  = b_base + bl;
  const int y0 = blockIdx.y * 64;
  const int t  = threadIdx.x;
  const int lane = t & 63, wave = t >> 6;
  const int t0 = blockIdx.y * 2;
  const int erow = t >> 2;
  const int eg0  = t & 3;
  const int tsel = t0 + (erow >> 5);

  v4f oacc[4][4];
#pragma unroll
  for (int kf = 0; kf < 4; ++kf)
#pragma unroll
    for (int yf = 0; yf < 4; ++yf) oacc[kf][yf] = (v4f){0.f, 0.f, 0.f, 0.f};

  // prologue: stage chunk 0
#pragma unroll
  for (int i = 0; i < 8; ++i) {
    int G = i * 256 + t;
    int r = G >> 3, sl = G & 7;
    size_t so = ((size_t)b * CO + r) * HW + ((sl ^ (r & 7)) << 3);
    gll16(&pem_h[so], &pml[0][(unsigned)((i * 256 + wave * 64) << 4)]);
  }
#pragma unroll
  for (int gi = 0; gi < 2; ++gi) {
    int g = eg0 + gi * 4;
    uint4 ev = *(const uint4*)&Ep[((size_t)bl * HW + y0 + erow) * HW + g * 8];
    uint4 sv = *(const uint4*)&s_h[((size_t)b * NCHUNK + tsel) * HW + g * 8];
    v8h e = __builtin_bit_cast(v8h, ev) * __builtin_bit_cast(v8h, sv);
    *(uint4*)&el[0][erow * 128 + ((g ^ (erow & 7)) << 4)] = __builtin_bit_cast(uint4, e);
  }
  __syncthreads();

  for (int tt = 0; tt < 64; ++tt) {
    const int cur = tt & 1, nxt = cur ^ 1;
    const int xn = (tt + 1) * 64;
    uint4 ev[2], sv[2];
    const bool pre = (tt < 63);
    if (pre) {
#pragma unroll
      for (int i = 0; i < 8; ++i) {
        int G = i * 256 + t;
        int r = G >> 3, sl = G & 7;
        size_t so = ((size_t)b * CO + r) * HW + xn + ((sl ^ (r & 7)) << 3);
        gll16(&pem_h[so], &pml[nxt][(unsigned)((i * 256 + wave * 64) << 4)]);
      }
#pragma unroll
      for (int gi = 0; gi < 2; ++gi) {
        int g = eg0 + gi * 4;
        ev[gi] = *(const uint4*)&Ep[((size_t)bl * HW + y0 + erow) * HW + xn + g * 8];
        sv[gi] = *(const uint4*)&s_h[((size_t)b * NCHUNK + tsel) * HW + xn + g * 8];
      }
    }
    // compute current chunk
#pragma unroll
    for (int st = 0; st < 2; ++st) {
      v8h af[4], bfr[4];
#pragma unroll
      for (int kf = 0; kf < 4; ++kf)
        af[kf] = lds_frag_h(pml[cur], wave * 64 + kf * 16 + (lane & 15),
                            st * 4 + (lane >> 4), 128);
#pragma unroll
      for (int yf = 0; yf < 4; ++yf)
        bfr[yf] = lds_frag_h(el[cur], yf * 16 + (lane & 15),
                             st * 4 + (lane >> 4), 128);
#pragma unroll
      for (int kf = 0; kf < 4; ++kf)
#pragma unroll
        for (int yf = 0; yf < 4; ++yf)
          oacc[kf][yf] = mfma16h(af[kf], bfr[yf], oacc[kf][yf]);
    }
    if (pre) {
#pragma unroll
      for (int gi = 0; gi < 2; ++gi) {
        int g = eg0 + gi * 4;
        v8h e = __builtin_bit_cast(v8h, ev[gi]) * __builtin_bit_cast(v8h, sv[gi]);
        *(uint4*)&el[nxt][erow * 128 + ((g ^ (erow & 7)) << 4)] =
            __builtin_bit_cast(uint4, e);
      }
    }
    __syncthreads();
  }

#pragma unroll
  for (int kf = 0; kf < 4; ++kf)
#pragma unroll
    for (int yf = 0; yf < 4; ++yf)
#pragma unroll
      for (int r = 0; r < 4; ++r) {
        int k = wave * 64 + kf * 16 + (lane >> 4) * 4 + r;
        int y = y0 + yf * 16 + (lane & 15);
        out[((size_t)b * CO + k) * HW + y] = oacc[kf][yf][r];
      }
}

// ===========================================================================
// Tier-2: round-2 MFMA kernels (ws >= 84MB, < half-tier)
// ===========================================================================
__global__ __launch_bounds__(512) void k_stats_mfma(
    const ushort_t* __restrict__ proj_hi, const ushort_t* __restrict__ proj_lo,
    const ushort_t* __restrict__ pem_t_hi, const ushort_t* __restrict__ pem_t_lo,
    float* __restrict__ Mx, float* __restrict__ Dinv) {
  __shared__ __align__(16) unsigned char pa[2 * 64 * 512];
  __shared__ __align__(16) unsigned char pb[2 * 64 * 512];
  const int bid = blockIdx.x;
  const int b = bid & 7, x0 = (bid >> 3) * 64;
  const int t = threadIdx.x;
  const int lane = t & 63, wave = t >> 6;
  const int wx = wave >> 1, wy = wave & 1;
  {
    const ushort_t* s1 = proj_hi + ((size_t)b * HW + x0) * CO;
    const ushort_t* s2 = proj_lo + ((size_t)b * HW + x0) * CO;
#pragma unroll
    for (int i = 0; i < 4; ++i) {
      int g = i * 512 + t;
      int r = g >> 5, sl = g & 31;
      *(uint4*)(pa + r * 512 + ((sl ^ (r & 7)) << 4)) =
          *(const uint4*)(s1 + (size_t)r * CO + sl * 8);
      *(uint4*)(pa + 64 * 512 + r * 512 + ((sl ^ (r & 7)) << 4)) =
          *(const uint4*)(s2 + (size_t)r * CO + sl * 8);
    }
  }
  float m[4], dsum[4];
#pragma unroll
  for (int r = 0; r < 4; ++r) { m[r] = -3.0e38f; dsum[r] = 0.f; }
  const int ar  = wx * 16 + (lane & 15);
  const int br0 = wy * 32 + (lane & 15);
  const int br1 = br0 + 16;
  for (int y0 = 0; y0 < HW; y0 += 64) {
    __syncthreads();
    const ushort_t* s1 = pem_t_hi + ((size_t)b * HW + y0) * CO;
    const ushort_t* s2 = pem_t_lo + ((size_t)b * HW + y0) * CO;
#pragma unroll
    for (int i = 0; i < 4; ++i) {
      int g = i * 512 + t;
      int r = g >> 5, sl = g & 31;
      *(uint4*)(pb + r * 512 + ((sl ^ (r & 7)) << 4)) =
          *(const uint4*)(s1 + (size_t)r * CO + sl * 8);
      *(uint4*)(pb + 64 * 512 + r * 512 + ((sl ^ (r & 7)) << 4)) =
          *(const uint4*)(s2 + (size_t)r * CO + sl * 8);
    }
    __syncthreads();
    v4f acc0 = {0.f, 0.f, 0.f, 0.f}, acc1 = {0.f, 0.f, 0.f, 0.f};
#pragma unroll
    for (int cs = 0; cs < 8; ++cs) {
      int cb = cs * 4 + (lane >> 4);
      v8bf ah  = lds_frag(pa, ar, cb, 512);
      v8bf al  = lds_frag(pa + 64 * 512, ar, cb, 512);
      v8bf bh0 = lds_frag(pb, br0, cb, 512);
      v8bf bl0 = lds_frag(pb + 64 * 512, br0, cb, 512);
      v8bf bh1 = lds_frag(pb, br1, cb, 512);
      v8bf bl1 = lds_frag(pb + 64 * 512, br1, cb, 512);
      acc0 = mfma16(ah, bh0, acc0);
      acc0 = mfma16(ah, bl0, acc0);
      acc0 = mfma16(al, bh0, acc0);
      acc1 = mfma16(ah, bh1, acc1);
      acc1 = mfma16(ah, bl1, acc1);
      acc1 = mfma16(al, bh1, acc1);
    }
#pragma unroll
    for (int r = 0; r < 4; ++r) {
      float mx = fmaxf(acc0[r], acc1[r]);
      mx = fmaxf(mx, __shfl_xor(mx, 1));
      mx = fmaxf(mx, __shfl_xor(mx, 2));
      mx = fmaxf(mx, __shfl_xor(mx, 4));
      mx = fmaxf(mx, __shfl_xor(mx, 8));
      if (mx > m[r]) { dsum[r] *= __expf(m[r] - mx); m[r] = mx; }
      float e = __expf(acc0[r] - m[r]) + __expf(acc1[r] - m[r]);
      e += __shfl_xor(e, 1);
      e += __shfl_xor(e, 2);
      e += __shfl_xor(e, 4);
      e += __shfl_xor(e, 8);
      dsum[r] += e;
    }
  }
  __syncthreads();
  float* redm = (float*)pb;
  float* redd = (float*)(pb + 4096);
  if ((lane & 15) == 0) {
#pragma unroll
    for (int r = 0; r < 4; ++r) {
      int xr = wx * 16 + (lane >> 4) * 4 + r;
      redm[xr * 2 + wy] = m[r];
      redd[xr * 2 + wy] = dsum[r];
    }
  }
  __syncthreads();
  if (t < 64) {
    float m0 = redm[t * 2], m1 = redm[t * 2 + 1];
    float mm = fmaxf(m0, m1);
    float dd = redd[t * 2] * __expf(m0 - mm) + redd[t * 2 + 1] * __expf(m1 - mm);
    Mx[(size_t)b * HW + x0 + t] = mm;
    Dinv[(size_t)b * HW + x0 + t] = 1.0f / dd;
  }
}

__global__ __launch_bounds__(512) void k_out_mfma(
    const ushort_t* __restrict__ proj_hi, const ushort_t* __restrict__ proj_lo,
    const ushort_t* __restrict__ pem_t_hi, const ushort_t* __restrict__ pem_t_lo,
    const ushort_t* __restrict__ pem_kx,
    const float* __restrict__ Mx, const float* __restrict__ Dinv,
    float* __restrict__ out) {
  __shared__ __align__(16) unsigned char pb[2 * 64 * 512];
  __shared__ __align__(16) unsigned char U1[2 * 64 * 512];
  __shared__ __align__(16) unsigned char Elds[64 * 128];
  __shared__ float Ms[64], Ds[64];
  const int bid = blockIdx.x;
  const int b = bid & 7, y0 = (bid >> 3) * 64;
  const int t = threadIdx.x;
  const int lane = t & 63, wave = t >> 6;
  const int wx = wave >> 1, wy = wave & 1;
  {
    const ushort_t* s1 = pem_t_hi + ((size_t)b * HW + y0) * CO;
    const ushort_t* s2 = pem_t_lo + ((size_t)b * HW + y0) * CO;
#pragma unroll
    for (int i = 0; i < 4; ++i) {
      int g = i * 512 + t;
      int r = g >> 5, sl = g & 31;
      *(uint4*)(pb + r * 512 + ((sl ^ (r & 7)) << 4)) =
          *(const uint4*)(s1 + (size_t)r * CO + sl * 8);
      *(uint4*)(pb + 64 * 512 + r * 512 + ((sl ^ (r & 7)) << 4)) =
          *(const uint4*)(s2 + (size_t)r * CO + sl * 8);
    }
  }
  v4f oacc[2][4];
#pragma unroll
  for (int kf = 0; kf < 2; ++kf)
#pragma unroll
    for (int yf = 0; yf < 4; ++yf) oacc[kf][yf] = (v4f){0.f, 0.f, 0.f, 0.f};
  const int ar  = wx * 16 + (lane & 15);
  const int br0 = wy * 32 + (lane & 15);
  const int br1 = br0 + 16;
  const int kb  = wave * 32;
  for (int x0 = 0; x0 < HW; x0 += 64) {
    __syncthreads();
    {
      const ushort_t* s1 = proj_hi + ((size_t)b * HW + x0) * CO;
      const ushort_t* s2 = proj_lo + ((size_t)b * HW + x0) * CO;
#pragma unroll
      for (int i = 0; i < 4; ++i) {
        int g = i * 512 + t;
        int r = g >> 5, sl = g & 31;
        *(uint4*)(U1 + r * 512 + ((sl ^ (r & 7)) << 4)) =
            *(const uint4*)(s1 + (size_t)r * CO + sl * 8);
        *(uint4*)(U1 + 64 * 512 + r * 512 + ((sl ^ (r & 7)) << 4)) =
            *(const uint4*)(s2 + (size_t)r * CO + sl * 8);
      }
      if (t < 64) Ms[t] = Mx[(size_t)b * HW + x0 + t];
      else if (t < 128) Ds[t - 64] = Dinv[(size_t)b * HW + x0 + t - 64];
    }
    __syncthreads();
    v4f s0 = {0.f, 0.f, 0.f, 0.f}, s1v = {0.f, 0.f, 0.f, 0.f};
#pragma unroll
    for (int cs = 0; cs < 8; ++cs) {
      int cb = cs * 4 + (lane >> 4);
      v8bf ah  = lds_frag(U1, ar, cb, 512);
      v8bf al  = lds_frag(U1 + 64 * 512, ar, cb, 512);
      v8bf bh0 = lds_frag(pb, br0, cb, 512);
      v8bf bl0 = lds_frag(pb + 64 * 512, br0, cb, 512);
      v8bf bh1 = lds_frag(pb, br1, cb, 512);
      v8bf bl1 = lds_frag(pb + 64 * 512, br1, cb, 512);
      s0  = mfma16(ah, bh0, s0);
      s0  = mfma16(ah, bl0, s0);
      s0  = mfma16(al, bh0, s0);
      s1v = mfma16(ah, bh1, s1v);
      s1v = mfma16(ah, bl1, s1v);
      s1v = mfma16(al, bh1, s1v);
    }
    {
      int xl0 = wx * 16 + (lane >> 4) * 4;
      float mv0 = Ms[xl0], mv1 = Ms[xl0 + 1], mv2 = Ms[xl0 + 2], mv3 = Ms[xl0 + 3];
      float dv0 = Ds[xl0], dv1 = Ds[xl0 + 1], dv2 = Ds[xl0 + 2], dv3 = Ds[xl0 + 3];
      int gx = xl0 >> 3;
      int off8 = (xl0 & 7) * 2;
      int yl0 = wy * 32 + (lane & 15);
      int yl1 = yl0 + 16;
      ushort4 p0, p1;
      p0.x = f2bf(__expf(s0[0] - mv0) * dv0);
      p0.y = f2bf(__expf(s0[1] - mv1) * dv1);
      p0.z = f2bf(__expf(s0[2] - mv2) * dv2);
      p0.w = f2bf(__expf(s0[3] - mv3) * dv3);
      p1.x = f2bf(__expf(s1v[0] - mv0) * dv0);
      p1.y = f2bf(__expf(s1v[1] - mv1) * dv1);
      p1.z = f2bf(__expf(s1v[2] - mv2) * dv2);
      p1.w = f2bf(__expf(s1v[3] - mv3) * dv3);
      *(ushort4*)(Elds + yl0 * 128 + ((gx ^ (yl0 & 7)) << 4) + off8) = p0;
      *(ushort4*)(Elds + yl1 * 128 + ((gx ^ (yl1 & 7)) << 4) + off8) = p1;
    }
    __syncthreads();
    {
      const ushort_t* s3 = pem_kx + (size_t)b * CO * HW + x0;
#pragma unroll
      for (int i = 0; i < 4; ++i) {
        int g = i * 512 + t;
        int r = g >> 3, sl = g & 7;
        *(uint4*)(U1 + r * 128 + ((sl ^ (r & 7)) << 4)) =
            *(const uint4*)(s3 + (size_t)r * HW + sl * 8);
      }
    }
    __syncthreads();
#pragma unroll
    for (int cs = 0; cs < 2; ++cs) {
      int cb = cs * 4 + (lane >> 4);
      v8bf a0 = lds_frag(U1, kb + (lane & 15), cb, 128);
      v8bf a1 = lds_frag(U1, kb + 16 + (lane & 15), cb, 128);
      v8bf e0 = lds_frag(Elds, 0 + (lane & 15), cb, 128);
      v8bf e1 = lds_frag(Elds, 16 + (lane & 15), cb, 128);
      v8bf e2 = lds_frag(Elds, 32 + (lane & 15), cb, 128);
      v8bf e3 = lds_frag(Elds, 48 + (lane & 15), cb, 128);
      oacc[0][0] = mfma16(a0, e0, oacc[0][0]);
      oacc[0][1] = mfma16(a0, e1, oacc[0][1]);
      oacc[0][2] = mfma16(a0, e2, oacc[0][2]);
      oacc[0][3] = mfma16(a0, e3, oacc[0][3]);
      oacc[1][0] = mfma16(a1, e0, oacc[1][0]);
      oacc[1][1] = mfma16(a1, e1, oacc[1][1]);
      oacc[1][2] = mfma16(a1, e2, oacc[1][2]);
      oacc[1][3] = mfma16(a1, e3, oacc[1][3]);
    }
  }
#pragma unroll
  for (int kf = 0; kf < 2; ++kf)
#pragma unroll
    for (int yf = 0; yf < 4; ++yf)
#pragma unroll
      for (int r = 0; r < 4; ++r) {
        int k = kb + kf * 16 + (lane >> 4) * 4 + r;
        int y = y0 + yf * 16 + (lane & 15);
        out[((size_t)b * CO + k) * HW + y] = oacc[kf][yf][r];
      }
}

// ===========================================================================
// fp32 fallback path
// ===========================================================================
__global__ __launch_bounds__(256) void k_proj(
    const float* __restrict__ x, const float* __restrict__ W,
    const float* __restrict__ bias, float* __restrict__ proj) {
  __shared__ float As[KT][68];
  __shared__ float Bs[KT][68];
  const int i0 = blockIdx.x * 64;
  const int o0 = blockIdx.y * 64;
  const int b  = blockIdx.z;
  const int t  = threadIdx.x;
  const int tx = t & 15, ty = t >> 4;
  const float* xb = x + (size_t)b * CIN * HW;
  float acc[4][4] = {};
  for (int c0 = 0; c0 < CIN; c0 += KT) {
#pragma unroll
    for (int l = 0; l < 8; ++l) {
      int idx = t + l * 256;
      int o = idx >> 5;
      int c = idx & 31;
      As[c][o] = W[(size_t)(o0 + o) * CIN + c0 + c];
    }
#pragma unroll
    for (int l = 0; l < 2; ++l) {
      int idx4 = t + l * 256;
      int c = idx4 >> 4;
      int i4 = idx4 & 15;
      *(float4*)&Bs[c][i4 * 4] =
          *(const float4*)&xb[(size_t)(c0 + c) * HW + i0 + i4 * 4];
    }
    __syncthreads();
#pragma unroll
    for (int c = 0; c < KT; ++c) {
      float4 a  = *(const float4*)&As[c][tx * 4];
      float4 bv = *(const float4*)&Bs[c][ty * 4];
      float av[4] = {a.x, a.y, a.z, a.w};
      float bb[4] = {bv.x, bv.y, bv.z, bv.w};
#pragma unroll
      for (int u = 0; u < 4; ++u)
#pragma unroll
        for (int v = 0; v < 4; ++v) acc[u][v] += av[u] * bb[v];
    }
    __syncthreads();
  }
  float* pbout = proj + (size_t)b * CO * HW;
#pragma unroll
  for (int u = 0; u < 4; ++u) {
    int o = o0 + tx * 4 + u;
    float bsv = bias[o];
    float4 r;
    r.x = acc[u][0] + bsv; r.y = acc[u][1] + bsv;
    r.z = acc[u][2] + bsv; r.w = acc[u][3] + bsv;
    *(float4*)&pbout[(size_t)o * HW + i0 + ty * 4] = r;
  }
}

__global__ __launch_bounds__(256) void k_stats(
    const float* __restrict__ proj, const float* __restrict__ pem,
    float* __restrict__ Mx, float* __restrict__ Dinv) {
  __shared__ float As[KT][68];
  __shared__ float Bs[KT][68];
  __shared__ float MsS[64][17];
  __shared__ float DsS[64][17];
  const int x0 = blockIdx.x * 64;
  const int b  = blockIdx.y;
  const int t  = threadIdx.x;
  const int tx = t & 15, ty = t >> 4;
  const float* pj = proj + (size_t)b * CO * HW;
  const float* pe = pem + (size_t)b * CO * HW;
  float m[4], d[4];
#pragma unroll
  for (int u = 0; u < 4; ++u) { m[u] = -3.0e38f; d[u] = 0.f; }
  for (int y0 = 0; y0 < HW; y0 += 64) {
    float s[4][4] = {};
    for (int c0 = 0; c0 < CO; c0 += KT) {
#pragma unroll
      for (int l = 0; l < 2; ++l) {
        int idx4 = t + l * 256;
        int c = idx4 >> 4, w4 = idx4 & 15;
        *(float4*)&As[c][w4 * 4] =
            *(const float4*)&pj[(size_t)(c0 + c) * HW + x0 + w4 * 4];
        *(float4*)&Bs[c][w4 * 4] =
            *(const float4*)&pe[(size_t)(c0 + c) * HW + y0 + w4 * 4];
      }
      __syncthreads();
#pragma unroll
      for (int c = 0; c < KT; ++c) {
        float4 a  = *(const float4*)&As[c][tx * 4];
        float4 bv = *(const float4*)&Bs[c][ty * 4];
        float av[4] = {a.x, a.y, a.z, a.w};
        float bb[4] = {bv.x, bv.y, bv.z, bv.w};
#pragma unroll
        for (int u = 0; u < 4; ++u)
#pragma unroll
          for (int v = 0; v < 4; ++v) s[u][v] += av[u] * bb[v];
      }
      __syncthreads();
    }
#pragma unroll
    for (int u = 0; u < 4; ++u) {
      float mv = fmaxf(fmaxf(s[u][0], s[u][1]), fmaxf(s[u][2], s[u][3]));
      if (mv > m[u]) { d[u] *= __expf(m[u] - mv); m[u] = mv; }
      d[u] += __expf(s[u][0] - m[u]) + __expf(s[u][1] - m[u]) +
              __expf(s[u][2] - m[u]) + __expf(s[u][3] - m[u]);
    }
  }
#pragma unroll
  for (int u = 0; u < 4; ++u) { MsS[tx * 4 + u][ty] = m[u]; DsS[tx * 4 + u][ty] = d[u]; }
  __syncthreads();
  if (t < 64) {
    float mm = -3.0e38f;
#pragma unroll
    for (int i = 0; i < 16; ++i) mm = fmaxf(mm, MsS[t][i]);
    float dd = 0.f;
#pragma unroll
    for (int i = 0; i < 16; ++i) dd += DsS[t][i] * __expf(MsS[t][i] - mm);
    Mx[(size_t)b * HW + x0 + t]   = mm;
    Dinv[(size_t)b * HW + x0 + t] = 1.0f / dd;
  }
}

__global__ __launch_bounds__(256) void k_out(
    const float* __restrict__ proj, const float* __restrict__ pem,
    const float* __restrict__ Mx, const float* __restrict__ Dinv,
    float* __restrict__ out) {
  __shared__ float As[KT][68];
  __shared__ float Bs[KT][68];
  __shared__ float E[64][68];
  const int y0 = blockIdx.x * 64;
  const int b  = blockIdx.y;
  const int t  = threadIdx.x;
  const int tx = t & 15, ty = t >> 4;
  const int kg = t >> 3, yg = t & 7;
  const float* pj = proj + (size_t)b * CO * HW;
  const float* pe = pem + (size_t)b * CO * HW;
  const float* Mb = Mx + (size_t)b * HW;
  const float* Db = Dinv + (size_t)b * HW;
  float acc[8][8] = {};
  for (int x0 = 0; x0 < HW; x0 += 64) {
    float s[4][4] = {};
    for (int c0 = 0; c0 < CO; c0 += KT) {
#pragma unroll
      for (int l = 0; l < 2; ++l) {
        int idx4 = t + l * 256;
        int c = idx4 >> 4, w4 = idx4 & 15;
        *(float4*)&As[c][w4 * 4] =
            *(const float4*)&pj[(size_t)(c0 + c) * HW + x0 + w4 * 4];
        *(float4*)&Bs[c][w4 * 4] =
            *(const float4*)&pe[(size_t)(c0 + c) * HW + y0 + w4 * 4];
      }
      __syncthreads();
#pragma unroll
      for (int c = 0; c < KT; ++c) {
        float4 a  = *(const float4*)&As[c][tx * 4];
        float4 bv = *(const float4*)&Bs[c][ty * 4];
        float av[4] = {a.x, a.y, a.z, a.w};
        float bb[4] = {bv.x, bv.y, bv.z, bv.w};
#pragma unroll
        for (int u = 0; u < 4; ++u)
#pragma unroll
          for (int v = 0; v < 4; ++v) s[u][v] += av[u] * bb[v];
      }
      __syncthreads();
    }
#pragma unroll
    for (int u = 0; u < 4; ++u) {
      int xr = x0 + tx * 4 + u;
      float mm = Mb[xr];
      float di = Db[xr];
      E[tx * 4 + u][ty * 4 + 0] = __expf(s[u][0] - mm) * di;
      E[tx * 4 + u][ty * 4 + 1] = __expf(s[u][1] - mm) * di;
      E[tx * 4 + u][ty * 4 + 2] = __expf(s[u][2] - mm) * di;
      E[tx * 4 + u][ty * 4 + 3] = __expf(s[u][3] - mm) * di;
    }
    __syncthreads();
    for (int xi = 0; xi < 64; xi += 4) {
      float4 p[8];
#pragma unroll
      for (int u = 0; u < 8; ++u)
        p[u] = *(const float4*)&pe[(size_t)(kg * 8 + u) * HW + x0 + xi];
#pragma unroll
      for (int j = 0; j < 4; ++j) {
        float4 e0 = *(const float4*)&E[xi + j][yg * 8];
        float4 e1 = *(const float4*)&E[xi + j][yg * 8 + 4];
        float ev[8] = {e0.x, e0.y, e0.z, e0.w, e1.x, e1.y, e1.z, e1.w};
#pragma unroll
        for (int u = 0; u < 8; ++u) {
          float a = (j == 0) ? p[u].x : (j == 1) ? p[u].y : (j == 2) ? p[u].z : p[u].w;
#pragma unroll
          for (int v = 0; v < 8; ++v) acc[u][v] += a * ev[v];
        }
      }
    }
    __syncthreads();
  }
#pragma unroll
  for (int u = 0; u < 8; ++u) {
    int k = kg * 8 + u;
    float4 r0, r1;
    r0.x = acc[u][0]; r0.y = acc[u][1]; r0.z = acc[u][2]; r0.w = acc[u][3];
    r1.x = acc[u][4]; r1.y = acc[u][5]; r1.z = acc[u][6]; r1.w = acc[u][7];
    float* ob = out + ((size_t)b * CO + k) * HW + y0 + yg * 8;
    *(float4*)&ob[0] = r0;
    *(float4*)&ob[4] = r1;
  }
}

// ===========================================================================
extern "C" void kernel_launch(void* const* d_in, const int* in_sizes, int n_in,
                              void* d_out, int out_size, void* d_ws, size_t ws_size,
                              hipStream_t stream) {
  const float* x    = (const float*)d_in[0];
  const float* pem  = (const float*)d_in[1];
  const float* W    = (const float*)d_in[2];
  const float* bias = (const float*)d_in[3];
  float* out = (float*)d_out;

  const size_t NS  = (size_t)BATCH * HW * CO;   // 8.39M
  const size_t HWB = (size_t)BATCH * HW;        // 32768
  const size_t SNAP = (size_t)BATCH * NCHUNK * HW;  // 4.19M

  unsigned char* base = (unsigned char*)d_ws;
  ushort_t* proj_hi  = (ushort_t*)base;
  ushort_t* proj_lo  = proj_hi + NS;
  ushort_t* pem_t_hi = proj_lo + NS;
  ushort_t* pem_t_lo = pem_t_hi + NS;
  ushort_t* pem_aux  = pem_t_lo + NS;
  float*    Mx       = (float*)(pem_aux + NS);
  float*    Dinv     = Mx + HWB;
  float*    m_snap   = Dinv + HWB;
  _Float16* s_h      = (_Float16*)(m_snap + SNAP);
  _Float16* Ep       = s_h + SNAP;

  const size_t need_tier2 = 5 * NS * 2 + 2 * HWB * 4;
  const size_t need_base  = need_tier2 + SNAP * 4 + SNAP * 2;
  const size_t e_full     = (size_t)BATCH * HW * HW * 2;   // 268.4MB
  const size_t need_big   = need_base + e_full;
  const size_t need_half  = need_base + e_full / 2;

  if (ws_size >= need_half) {
    k_proj_split<<<dim3(HW / 64, CO / 64, BATCH), 256, 0, stream>>>(
        x, W, bias, proj_hi, proj_lo);
    k_tr_pem<<<dim3(HW / 64, CO / 64, BATCH), 256, 0, stream>>>(
        pem, pem_t_hi, pem_t_lo, pem_aux, 1);
    const _Float16* pem_h = (const _Float16*)pem_aux;
    if (ws_size >= need_big) {
      k_pass1<<<dim3(BATCH, HW / 128), 256, 0, stream>>>(
          proj_hi, proj_lo, pem_t_hi, pem_t_lo, Ep, m_snap, Mx, Dinv, 0);
      k_sfin<<<BATCH * NCHUNK, 256, 0, stream>>>(m_snap, Mx, Dinv, s_h);
      k_pass2<<<dim3(BATCH, HW / 64), 256, 0, stream>>>(Ep, pem_h, s_h, out, 0);
    } else {
      for (int h = 0; h < 2; ++h) {
        int b_base = h * 4;
        k_pass1<<<dim3(4, HW / 128), 256, 0, stream>>>(
            proj_hi, proj_lo, pem_t_hi, pem_t_lo, Ep, m_snap, Mx, Dinv, b_base);
        k_sfin<<<BATCH * NCHUNK, 256, 0, stream>>>(m_snap, Mx, Dinv, s_h);
        k_pass2<<<dim3(4, HW / 64), 256, 0, stream>>>(Ep, pem_h, s_h, out, b_base);
      }
    }
  } else if (ws_size >= need_tier2) {
    k_proj_split<<<dim3(HW / 64, CO / 64, BATCH), 256, 0, stream>>>(
        x, W, bias, proj_hi, proj_lo);
    k_tr_pem<<<dim3(HW / 64, CO / 64, BATCH), 256, 0, stream>>>(
        pem, pem_t_hi, pem_t_lo, pem_aux, 0);
    k_stats_mfma<<<dim3(512), 512, 0, stream>>>(
        proj_hi, proj_lo, pem_t_hi, pem_t_lo, Mx, Dinv);
    k_out_mfma<<<dim3(512), 512, 0, stream>>>(
        proj_hi, proj_lo, pem_t_hi, pem_t_lo, pem_aux, Mx, Dinv, out);
  } else {
    float* proj = (float*)d_ws;
    float* Mx2  = proj + NS;
    float* Di2  = Mx2 + HWB;
    const size_t need = (NS + 2 * HWB) * sizeof(float);
    if (ws_size < need) return;
    k_proj <<<dim3(HW / 64, CO / 64, BATCH), 256, 0, stream>>>(x, W, bias, proj);
    k_stats<<<dim3(HW / 64, BATCH),          256, 0, stream>>>(proj, pem, Mx2, Di2);
    k_out  <<<dim3(HW / 64, BATCH),          256, 0, stream>>>(proj, pem, Mx2, Di2, out);
  }
}

// Round 4
// 479.937 us; speedup vs baseline: 2.1048x; 2.1048x over previous
//
#include <hip/hip_runtime.h>
#include <math.h>

#define BATCH 8
#define CIN 512
#define CO 256
#define HW 4096
#define KT 32
#define NCHUNK 128          // total y-chunks of 32
#define NSEG 4
#define SEGC (NCHUNK / NSEG)

typedef unsigned short ushort_t;
typedef unsigned int uint_t;
typedef __bf16 v8bf __attribute__((ext_vector_type(8)));
typedef _Float16 v8h __attribute__((ext_vector_type(8)));
typedef _Float16 v4h __attribute__((ext_vector_type(4)));
typedef float v4f __attribute__((ext_vector_type(4)));
typedef ushort_t u16x8 __attribute__((ext_vector_type(8)));

__device__ __forceinline__ ushort_t f2bf(float f) {
  uint_t u = __float_as_uint(f);
  u += 0x7FFFu + ((u >> 16) & 1u);
  return (ushort_t)(u >> 16);
}
__device__ __forceinline__ float bf2f(ushort_t h) {
  return __uint_as_float(((uint_t)h) << 16);
}
__device__ __forceinline__ v4f mfma16(v8bf a, v8bf b, v4f c) {
  return __builtin_amdgcn_mfma_f32_16x16x32_bf16(a, b, c, 0, 0, 0);
}
__device__ __forceinline__ v4f mfma16h(v8h a, v8h b, v4f c) {
  return __builtin_amdgcn_mfma_f32_16x16x32_f16(a, b, c, 0, 0, 0);
}
// pitch-512B tile, granule-XOR by (row&7)
__device__ __forceinline__ v8bf lds_frag(const unsigned char* base, int row, int cb) {
  uint4 v = *(const uint4*)(base + row * 512 + (((cb) ^ (row & 7)) << 4));
  return __builtin_bit_cast(v8bf, v);
}
// pitch-256B tile, granule-XOR by (row&15)
__device__ __forceinline__ v8h lds_frag_h16(const unsigned char* base, int row, int cb) {
  uint4 v = *(const uint4*)(base + row * 256 + (((cb) ^ (row & 15)) << 4));
  return __builtin_bit_cast(v8h, v);
}
__device__ __forceinline__ void gll16(const void* g, void* l) {
  __builtin_amdgcn_global_load_lds(
      (const __attribute__((address_space(1))) unsigned int*)g,
      (__attribute__((address_space(3))) unsigned int*)l, 16, 0, 0);
}

// ===========================================================================
// proj = W@x + bias (fp32 VALU), split-bf16, transposed [b][x][c].
// Epilogue goes through LDS so global stores are 32B-coalesced.
// ===========================================================================
__global__ __launch_bounds__(256) void k_proj_split(
    const float* __restrict__ x, const float* __restrict__ W,
    const float* __restrict__ bias,
    ushort_t* __restrict__ proj_hi, ushort_t* __restrict__ proj_lo) {
  __shared__ float As[KT][68];   // [c][o]
  __shared__ float Bs[KT][68];   // [c][i]
  __shared__ ushort_t Th[64][72];
  __shared__ ushort_t Tl[64][72];
  const int i0 = blockIdx.x * 64;
  const int o0 = blockIdx.y * 64;
  const int b  = blockIdx.z;
  const int t  = threadIdx.x;
  const int tx = t & 15, ty = t >> 4;
  const float* xb = x + (size_t)b * CIN * HW;
  float acc[4][4] = {};
  for (int c0 = 0; c0 < CIN; c0 += KT) {
#pragma unroll
    for (int l = 0; l < 8; ++l) {
      int idx = t + l * 256;
      int o = idx >> 5;
      int c = idx & 31;
      As[c][o] = W[(size_t)(o0 + o) * CIN + c0 + c];
    }
#pragma unroll
    for (int l = 0; l < 2; ++l) {
      int idx4 = t + l * 256;
      int c = idx4 >> 4;
      int i4 = idx4 & 15;
      *(float4*)&Bs[c][i4 * 4] =
          *(const float4*)&xb[(size_t)(c0 + c) * HW + i0 + i4 * 4];
    }
    __syncthreads();
#pragma unroll
    for (int c = 0; c < KT; ++c) {
      float4 a  = *(const float4*)&As[c][tx * 4];
      float4 bv = *(const float4*)&Bs[c][ty * 4];
      float av[4] = {a.x, a.y, a.z, a.w};
      float bb[4] = {bv.x, bv.y, bv.z, bv.w};
#pragma unroll
      for (int u = 0; u < 4; ++u)
#pragma unroll
        for (int v = 0; v < 4; ++v) acc[u][v] += av[u] * bb[v];
    }
    __syncthreads();
  }
  float bs[4];
#pragma unroll
  for (int u = 0; u < 4; ++u) bs[u] = bias[o0 + tx * 4 + u];
#pragma unroll
  for (int v = 0; v < 4; ++v) {
    ushort4 hi, lo;
    float z0 = acc[0][v] + bs[0];
    float z1 = acc[1][v] + bs[1];
    float z2 = acc[2][v] + bs[2];
    float z3 = acc[3][v] + bs[3];
    hi.x = f2bf(z0); hi.y = f2bf(z1); hi.z = f2bf(z2); hi.w = f2bf(z3);
    lo.x = f2bf(z0 - bf2f(hi.x)); lo.y = f2bf(z1 - bf2f(hi.y));
    lo.z = f2bf(z2 - bf2f(hi.z)); lo.w = f2bf(z3 - bf2f(hi.w));
    *(ushort4*)&Th[ty * 4 + v][tx * 4] = hi;
    *(ushort4*)&Tl[ty * 4 + v][tx * 4] = lo;
  }
  __syncthreads();
  {
    int row = t >> 2;
    int cs  = (t & 3) * 16;
    size_t off = ((size_t)b * HW + i0 + row) * CO + o0 + cs;
    uint4 h0 = *(uint4*)&Th[row][cs];
    uint4 h1 = *(uint4*)&Th[row][cs + 8];
    uint4 l0 = *(uint4*)&Tl[row][cs];
    uint4 l1 = *(uint4*)&Tl[row][cs + 8];
    *(uint4*)&proj_hi[off]     = h0;
    *(uint4*)&proj_hi[off + 8] = h1;
    *(uint4*)&proj_lo[off]     = l0;
    *(uint4*)&proj_lo[off + 8] = l1;
  }
}

// ===========================================================================
// pem [b][c][y] fp32 -> pem_t[b][y][c] hi/lo bf16 (coalesced via LDS) and
//                       pem_h[b][c][y] f16 (coalesced direct)
// ===========================================================================
__global__ __launch_bounds__(256) void k_tr_pem(
    const float* __restrict__ pem,
    ushort_t* __restrict__ pem_t_hi, ushort_t* __restrict__ pem_t_lo,
    ushort_t* __restrict__ pem_h) {
  __shared__ float T[64][65];  // [c][y]
  const int y0 = blockIdx.x * 64;
  const int c0 = blockIdx.y * 64;
  const int b  = blockIdx.z;
  const int t  = threadIdx.x;
  const int cl = t >> 4;
  const int y4 = (t & 15) * 4;
#pragma unroll
  for (int r = 0; r < 4; ++r) {
    int c = c0 + r * 16 + cl;
    size_t off = ((size_t)b * CO + c) * HW + y0 + y4;
    float4 v = *(const float4*)&pem[off];
    ushort4 h;
    h.x = __builtin_bit_cast(ushort_t, (_Float16)v.x);
    h.y = __builtin_bit_cast(ushort_t, (_Float16)v.y);
    h.z = __builtin_bit_cast(ushort_t, (_Float16)v.z);
    h.w = __builtin_bit_cast(ushort_t, (_Float16)v.w);
    *(ushort4*)&pem_h[off] = h;
    T[r * 16 + cl][y4 + 0] = v.x;
    T[r * 16 + cl][y4 + 1] = v.y;
    T[r * 16 + cl][y4 + 2] = v.z;
    T[r * 16 + cl][y4 + 3] = v.w;
  }
  __syncthreads();
  {
    int yl = t >> 2;
    int cs = (t & 3) * 16;
    u16x8 h0, h1, l0, l1;
#pragma unroll
    for (int j = 0; j < 8; ++j) {
      float f = T[cs + j][yl];
      ushort_t h = f2bf(f);
      h0[j] = h;
      l0[j] = f2bf(f - bf2f(h));
    }
#pragma unroll
    for (int j = 0; j < 8; ++j) {
      float f = T[cs + 8 + j][yl];
      ushort_t h = f2bf(f);
      h1[j] = h;
      l1[j] = f2bf(f - bf2f(h));
    }
    size_t ro = ((size_t)b * HW + y0 + yl) * CO + c0 + cs;
    *(u16x8*)&pem_t_hi[ro]     = h0;
    *(u16x8*)&pem_t_hi[ro + 8] = h1;
    *(u16x8*)&pem_t_lo[ro]     = l0;
    *(u16x8*)&pem_t_lo[ro + 8] = l1;
  }
}

// ===========================================================================
// Pass 1: stats + E' materialization, y-segmented.
// grid: nb * 32(xt) * 4(seg). Block: 256 thr, x-tile 128, A in registers.
// Defer-max (THR=8): d per-lane, rescale only when row max grows > 8.
// E' flushed coalesced via LDS transpose -> Ep[bl*32+xt][y][128] f16.
// ===========================================================================
__global__ __launch_bounds__(256, 2) void k_pass1(
    const ushort_t* __restrict__ proj_hi, const ushort_t* __restrict__ proj_lo,
    const ushort_t* __restrict__ pem_t_hi, const ushort_t* __restrict__ pem_t_lo,
    _Float16* __restrict__ Ep, float* __restrict__ m_snap,
    float* __restrict__ m_seg, float* __restrict__ d_seg,
    int nb, int b_base) {
  __shared__ __align__(16) unsigned char pbuf[2][2][32 * 512];  // 64 KB
  __shared__ __align__(16) unsigned char Etr[2][32 * 256];      // 16 KB
  const int id = blockIdx.x;
  const int brel = id % nb;
  const int b = b_base + brel;
  const int rest = id / nb;
  const int xt = rest & 31;
  const int seg = rest >> 5;
  const int x0 = xt * 128;
  const int t = threadIdx.x;
  const int lane = t & 63, wave = t >> 6;
  const int xw = x0 + wave * 32;

  // A fragments resident in registers (proj hi/lo, K=256)
  v8bf Ah[2][8], Al[2][8];
#pragma unroll
  for (int xf = 0; xf < 2; ++xf) {
    const size_t ro =
        ((size_t)b * HW + xw + xf * 16 + (lane & 15)) * CO + (lane >> 4) * 8;
#pragma unroll
    for (int st = 0; st < 8; ++st) {
      Ah[xf][st] = __builtin_bit_cast(v8bf, *(const uint4*)&proj_hi[ro + st * 32]);
      Al[xf][st] = __builtin_bit_cast(v8bf, *(const uint4*)&proj_lo[ro + st * 32]);
    }
  }

  float m[2][4], d[2][4];
#pragma unroll
  for (int xf = 0; xf < 2; ++xf)
#pragma unroll
    for (int r = 0; r < 4; ++r) { m[xf][r] = -3.0e38f; d[xf][r] = 0.f; }

  auto stage = [&](int bufi, int tt) {
    const int yy0 = tt * 32;
#pragma unroll
    for (int i = 0; i < 4; ++i) {
      int G = i * 256 + t;
      int r = G >> 5, sl = G & 31;
      size_t so = ((size_t)b * HW + yy0 + r) * CO + ((sl ^ (r & 7)) << 3);
      unsigned lb = (unsigned)((i * 256 + wave * 64) << 4);
      gll16(&pem_t_hi[so], &pbuf[bufi][0][lb]);
      gll16(&pem_t_lo[so], &pbuf[bufi][1][lb]);
    }
  };

  const int tt0 = seg * SEGC;
  stage(0, tt0);
  __syncthreads();

  for (int tc = 0; tc < SEGC; ++tc) {
    const int tt = tt0 + tc;
    if (tc + 1 < SEGC) stage((tc + 1) & 1, tt + 1);

    const unsigned char* bh_p = pbuf[tc & 1][0];
    const unsigned char* bl_p = pbuf[tc & 1][1];
    v4f acc[2][2];
#pragma unroll
    for (int xf = 0; xf < 2; ++xf)
#pragma unroll
      for (int yc = 0; yc < 2; ++yc) acc[xf][yc] = (v4f){0.f, 0.f, 0.f, 0.f};

#pragma unroll
    for (int st = 0; st < 8; ++st) {
#pragma unroll
      for (int yc = 0; yc < 2; ++yc) {
        int row = yc * 16 + (lane & 15);
        int cb  = st * 4 + (lane >> 4);
        v8bf bh = lds_frag(bh_p, row, cb);
        v8bf bv = lds_frag(bl_p, row, cb);
        acc[0][yc] = mfma16(Ah[0][st], bh, acc[0][yc]);
        acc[1][yc] = mfma16(Ah[1][st], bh, acc[1][yc]);
        acc[0][yc] = mfma16(Al[0][st], bh, acc[0][yc]);
        acc[1][yc] = mfma16(Al[1][st], bh, acc[1][yc]);
        acc[0][yc] = mfma16(Ah[0][st], bv, acc[0][yc]);
        acc[1][yc] = mfma16(Ah[1][st], bv, acc[1][yc]);
      }
    }

    // ---- defer-max stats + E' ----
#pragma unroll
    for (int xf = 0; xf < 2; ++xf) {
      float mx8 = fmaxf(fmaxf(fmaxf(acc[xf][0][0], acc[xf][0][1]),
                              fmaxf(acc[xf][0][2], acc[xf][0][3])),
                        fmaxf(fmaxf(acc[xf][1][0], acc[xf][1][1]),
                              fmaxf(acc[xf][1][2], acc[xf][1][3])));
      float minm = fminf(fminf(m[xf][0], m[xf][1]), fminf(m[xf][2], m[xf][3]));
      if (__any(mx8 > minm + 8.0f)) {
#pragma unroll
        for (int r = 0; r < 4; ++r) {
          float rm = fmaxf(acc[xf][0][r], acc[xf][1][r]);
          rm = fmaxf(rm, __shfl_xor(rm, 1));
          rm = fmaxf(rm, __shfl_xor(rm, 2));
          rm = fmaxf(rm, __shfl_xor(rm, 4));
          rm = fmaxf(rm, __shfl_xor(rm, 8));
          float mn = fmaxf(m[xf][r], rm);
          d[xf][r] *= __expf(m[xf][r] - mn);
          m[xf][r] = mn;
        }
      }
      v4h p0, p1;
#pragma unroll
      for (int r = 0; r < 4; ++r) {
        float e0 = __expf(acc[xf][0][r] - m[xf][r]);
        float e1 = __expf(acc[xf][1][r] - m[xf][r]);
        d[xf][r] += e0 + e1;
        p0[r] = (_Float16)e0;
        p1[r] = (_Float16)e1;
      }
      {
        int gx = (wave * 32 + xf * 16 + (lane >> 4) * 4) >> 3;
        int half = (lane >> 4) & 1;
        int y0l = lane & 15, y1l = 16 + (lane & 15);
        *(uint2*)&Etr[tc & 1][y0l * 256 + ((gx ^ (y0l & 15)) << 4) + half * 8] =
            __builtin_bit_cast(uint2, p0);
        *(uint2*)&Etr[tc & 1][y1l * 256 + ((gx ^ (y1l & 15)) << 4) + half * 8] =
            __builtin_bit_cast(uint2, p1);
      }
      if ((lane & 15) == 0) {
        *(float4*)&m_snap[((size_t)b * NCHUNK + tt) * HW + xw + xf * 16 +
                          (lane >> 4) * 4] =
            make_float4(m[xf][0], m[xf][1], m[xf][2], m[xf][3]);
      }
    }
    __syncthreads();  // Etr ready; gll16 drained; pbuf[cur] reads done
    // ---- flush Etr -> Ep (coalesced 32B per thread) ----
    {
      int yr = t >> 3;
      int g0 = (t & 7) * 2, g1 = g0 + 1;
      uint4 v0 = *(uint4*)&Etr[tc & 1][yr * 256 + ((g0 ^ (yr & 15)) << 4)];
      uint4 v1 = *(uint4*)&Etr[tc & 1][yr * 256 + ((g1 ^ (yr & 15)) << 4)];
      size_t go = (((size_t)(brel * 32 + xt)) * HW + (size_t)tt * 32 + yr) * 128;
      *(uint4*)&Ep[go + g0 * 8] = v0;
      *(uint4*)&Ep[go + g1 * 8] = v1;
    }
  }

  // ---- segment (m, d) out ----
#pragma unroll
  for (int xf = 0; xf < 2; ++xf) {
    float dv[4];
#pragma unroll
    for (int r = 0; r < 4; ++r) {
      float v = d[xf][r];
      v += __shfl_xor(v, 1);
      v += __shfl_xor(v, 2);
      v += __shfl_xor(v, 4);
      v += __shfl_xor(v, 8);
      dv[r] = v;
    }
    if ((lane & 15) == 0) {
      size_t o = ((size_t)(b * NSEG + seg)) * HW + xw + xf * 16 + (lane >> 4) * 4;
      *(float4*)&m_seg[o] = make_float4(m[xf][0], m[xf][1], m[xf][2], m[xf][3]);
      *(float4*)&d_seg[o] = make_float4(dv[0], dv[1], dv[2], dv[3]);
    }
  }
}

// ===========================================================================
// Merge segments -> Mx, Dinv
// ===========================================================================
__global__ __launch_bounds__(256) void k_red(
    const float* __restrict__ m_seg, const float* __restrict__ d_seg,
    float* __restrict__ Mx, float* __restrict__ Dinv, int b_base) {
  int idx = blockIdx.x * 256 + threadIdx.x;
  int b = b_base + (idx >> 12);
  int xx = idx & 4095;
  float ms[NSEG], ds[NSEG];
  float mm = -3.0e38f;
#pragma unroll
  for (int s = 0; s < NSEG; ++s) {
    ms[s] = m_seg[((size_t)(b * NSEG + s)) * HW + xx];
    ds[s] = d_seg[((size_t)(b * NSEG + s)) * HW + xx];
    mm = fmaxf(mm, ms[s]);
  }
  float dd = 0.f;
#pragma unroll
  for (int s = 0; s < NSEG; ++s) dd += ds[s] * __expf(ms[s] - mm);
  Mx[(size_t)b * HW + xx]   = mm;
  Dinv[(size_t)b * HW + xx] = 1.0f / dd;
}

// ===========================================================================
// Pass 2: out[b,k,y] = sum_x pem[k,x] * s(tt(y),x) * E'[x,y]  (f16 MFMA)
// grid: nb * 64(yt) * 2(kh). Block 256 thr, k-tile 128, y-tile 64,
// x loop over 32 chunks of 128. pml via gll16 (pre-swizzled src), el via
// VGPR (Ep contiguous 16KB slab * s from LDS), s computed 1 exp/thread/chunk.
// ===========================================================================
__global__ __launch_bounds__(256, 2) void k_pass2(
    const _Float16* __restrict__ Ep, const ushort_t* __restrict__ pem_h_u,
    const float* __restrict__ m_snap, const float* __restrict__ Mx,
    const float* __restrict__ Dinv, float* __restrict__ out,
    int nb, int b_base) {
  __shared__ __align__(16) unsigned char pml[128 * 256];   // 32 KB
  __shared__ __align__(16) unsigned char el[2][64 * 256];  // 32 KB
  __shared__ __align__(16) _Float16 slds[2][256];
  const int id = blockIdx.x;
  const int brel = id % nb;
  const int b = b_base + brel;
  const int rest = id / nb;
  const int kh = rest & 1;
  const int yt = rest >> 1;
  const int y0 = yt * 64;
  const int t = threadIdx.x;
  const int lane = t & 63, wave = t >> 6;
  const _Float16* pem_h = (const _Float16*)pem_h_u;

  v4f oacc[2][4];
#pragma unroll
  for (int kf = 0; kf < 2; ++kf)
#pragma unroll
    for (int yf = 0; yf < 4; ++yf) oacc[kf][yf] = (v4f){0.f, 0.f, 0.f, 0.f};

  auto stage_pml = [&](int xt) {
#pragma unroll
    for (int i = 0; i < 8; ++i) {
      int G = i * 256 + t;
      int r = G >> 4, sl = G & 15;
      size_t so = ((size_t)b * CO + kh * 128 + r) * HW + xt * 128 +
                  ((sl ^ (r & 15)) << 3);
      gll16(&pem_h[so], &pml[(unsigned)((i * 256 + wave * 64) << 4)]);
    }
  };
  auto load_el = [&](int xt, uint4* ev) {
    const size_t slab = ((size_t)(brel * 32 + xt)) * HW * 128;
#pragma unroll
    for (int i = 0; i < 4; ++i) {
      int G = i * 256 + t;
      ev[i] = *(const uint4*)&Ep[slab + (size_t)(y0 + (G >> 4)) * 128 +
                                 (G & 15) * 8];
    }
  };
  auto comp_s = [&](int bufi, int xt) {
    int ttrel = t >> 7, xr = t & 127;
    int ttg = (y0 >> 5) + ttrel;
    size_t xg = (size_t)xt * 128 + xr;
    float ms = m_snap[((size_t)b * NCHUNK + ttg) * HW + xg];
    float s = __expf(ms - Mx[(size_t)b * HW + xg]) * Dinv[(size_t)b * HW + xg];
    slds[bufi][ttrel * 128 + xr] = (_Float16)s;
  };
  auto write_el = [&](int bufi, const uint4* ev) {
#pragma unroll
    for (int i = 0; i < 4; ++i) {
      int G = i * 256 + t;
      int yl = G >> 4, sl = G & 15;
      v8h e = __builtin_bit_cast(v8h, ev[i]);
      v8h s = *(const v8h*)&slds[bufi][(yl >> 5) * 128 + sl * 8];
      e = e * s;
      *(uint4*)&el[bufi][yl * 256 + ((sl ^ (yl & 15)) << 4)] =
          __builtin_bit_cast(uint4, e);
    }
  };

  uint4 ev[4];
  // prologue
  comp_s(0, 0);
  load_el(0, ev);
  stage_pml(0);
  __syncthreads();          // slds[0] visible, pml(0) ready
  write_el(0, ev);
  comp_s(1, 1);
  __syncthreads();          // el[0], slds[1] visible

  for (int xt = 0; xt < 32; ++xt) {
    const int cur = xt & 1, nxt = cur ^ 1;
    if (xt + 1 < 32) load_el(xt + 1, ev);
    // ---- MFMA ----
#pragma unroll
    for (int st = 0; st < 4; ++st) {
      int cb = st * 4 + (lane >> 4);
      v8h af0 = lds_frag_h16(pml, wave * 32 + (lane & 15), cb);
      v8h af1 = lds_frag_h16(pml, wave * 32 + 16 + (lane & 15), cb);
      v8h bf0 = lds_frag_h16(el[cur], 0 + (lane & 15), cb);
      v8h bf1 = lds_frag_h16(el[cur], 16 + (lane & 15), cb);
      v8h bf2 = lds_frag_h16(el[cur], 32 + (lane & 15), cb);
      v8h bf3 = lds_frag_h16(el[cur], 48 + (lane & 15), cb);
      oacc[0][0] = mfma16h(af0, bf0, oacc[0][0]);
      oacc[0][1] = mfma16h(af0, bf1, oacc[0][1]);
      oacc[0][2] = mfma16h(af0, bf2, oacc[0][2]);
      oacc[0][3] = mfma16h(af0, bf3, oacc[0][3]);
      oacc[1][0] = mfma16h(af1, bf0, oacc[1][0]);
      oacc[1][1] = mfma16h(af1, bf1, oacc[1][1]);
      oacc[1][2] = mfma16h(af1, bf2, oacc[1][2]);
      oacc[1][3] = mfma16h(af1, bf3, oacc[1][3]);
    }
    __syncthreads();        // pml/el[cur] reads done by all waves
    if (xt + 1 < 32) {
      stage_pml(xt + 1);
      write_el(nxt, ev);
      if (xt + 2 < 32) comp_s(cur, xt + 2);
    }
    __syncthreads();        // gll16 drained; el[nxt]/slds visible
  }

#pragma unroll
  for (int kf = 0; kf < 2; ++kf)
#pragma unroll
    for (int yf = 0; yf < 4; ++yf)
#pragma unroll
      for (int r = 0; r < 4; ++r) {
        int k = kh * 128 + wave * 32 + kf * 16 + (lane >> 4) * 4 + r;
        int y = y0 + yf * 16 + (lane & 15);
        out[((size_t)b * CO + k) * HW + y] = oacc[kf][yf][r];
      }
}

// ===========================================================================
// fp32 fallback path (used only if ws is too small)
// ===========================================================================
__global__ __launch_bounds__(256) void k_proj(
    const float* __restrict__ x, const float* __restrict__ W,
    const float* __restrict__ bias, float* __restrict__ proj) {
  __shared__ float As[KT][68];
  __shared__ float Bs[KT][68];
  const int i0 = blockIdx.x * 64;
  const int o0 = blockIdx.y * 64;
  const int b  = blockIdx.z;
  const int t  = threadIdx.x;
  const int tx = t & 15, ty = t >> 4;
  const float* xb = x + (size_t)b * CIN * HW;
  float acc[4][4] = {};
  for (int c0 = 0; c0 < CIN; c0 += KT) {
#pragma unroll
    for (int l = 0; l < 8; ++l) {
      int idx = t + l * 256;
      int o = idx >> 5;
      int c = idx & 31;
      As[c][o] = W[(size_t)(o0 + o) * CIN + c0 + c];
    }
#pragma unroll
    for (int l = 0; l < 2; ++l) {
      int idx4 = t + l * 256;
      int c = idx4 >> 4;
      int i4 = idx4 & 15;
      *(float4*)&Bs[c][i4 * 4] =
          *(const float4*)&xb[(size_t)(c0 + c) * HW + i0 + i4 * 4];
    }
    __syncthreads();
#pragma unroll
    for (int c = 0; c < KT; ++c) {
      float4 a  = *(const float4*)&As[c][tx * 4];
      float4 bv = *(const float4*)&Bs[c][ty * 4];
      float av[4] = {a.x, a.y, a.z, a.w};
      float bb[4] = {bv.x, bv.y, bv.z, bv.w};
#pragma unroll
      for (int u = 0; u < 4; ++u)
#pragma unroll
        for (int v = 0; v < 4; ++v) acc[u][v] += av[u] * bb[v];
    }
    __syncthreads();
  }
  float* pbout = proj + (size_t)b * CO * HW;
#pragma unroll
  for (int u = 0; u < 4; ++u) {
    int o = o0 + tx * 4 + u;
    float bsv = bias[o];
    float4 r;
    r.x = acc[u][0] + bsv; r.y = acc[u][1] + bsv;
    r.z = acc[u][2] + bsv; r.w = acc[u][3] + bsv;
    *(float4*)&pbout[(size_t)o * HW + i0 + ty * 4] = r;
  }
}

__global__ __launch_bounds__(256) void k_stats(
    const float* __restrict__ proj, const float* __restrict__ pem,
    float* __restrict__ Mx, float* __restrict__ Dinv) {
  __shared__ float As[KT][68];
  __shared__ float Bs[KT][68];
  __shared__ float MsS[64][17];
  __shared__ float DsS[64][17];
  const int x0 = blockIdx.x * 64;
  const int b  = blockIdx.y;
  const int t  = threadIdx.x;
  const int tx = t & 15, ty = t >> 4;
  const float* pj = proj + (size_t)b * CO * HW;
  const float* pe = pem + (size_t)b * CO * HW;
  float m[4], d[4];
#pragma unroll
  for (int u = 0; u < 4; ++u) { m[u] = -3.0e38f; d[u] = 0.f; }
  for (int y0 = 0; y0 < HW; y0 += 64) {
    float s[4][4] = {};
    for (int c0 = 0; c0 < CO; c0 += KT) {
#pragma unroll
      for (int l = 0; l < 2; ++l) {
        int idx4 = t + l * 256;
        int c = idx4 >> 4, w4 = idx4 & 15;
        *(float4*)&As[c][w4 * 4] =
            *(const float4*)&pj[(size_t)(c0 + c) * HW + x0 + w4 * 4];
        *(float4*)&Bs[c][w4 * 4] =
            *(const float4*)&pe[(size_t)(c0 + c) * HW + y0 + w4 * 4];
      }
      __syncthreads();
#pragma unroll
      for (int c = 0; c < KT; ++c) {
        float4 a  = *(const float4*)&As[c][tx * 4];
        float4 bv = *(const float4*)&Bs[c][ty * 4];
        float av[4] = {a.x, a.y, a.z, a.w};
        float bb[4] = {bv.x, bv.y, bv.z, bv.w};
#pragma unroll
        for (int u = 0; u < 4; ++u)
#pragma unroll
          for (int v = 0; v < 4; ++v) s[u][v] += av[u] * bb[v];
      }
      __syncthreads();
    }
#pragma unroll
    for (int u = 0; u < 4; ++u) {
      float mv = fmaxf(fmaxf(s[u][0], s[u][1]), fmaxf(s[u][2], s[u][3]));
      if (mv > m[u]) { d[u] *= __expf(m[u] - mv); m[u] = mv; }
      d[u] += __expf(s[u][0] - m[u]) + __expf(s[u][1] - m[u]) +
              __expf(s[u][2] - m[u]) + __expf(s[u][3] - m[u]);
    }
  }
#pragma unroll
  for (int u = 0; u < 4; ++u) { MsS[tx * 4 + u][ty] = m[u]; DsS[tx * 4 + u][ty] = d[u]; }
  __syncthreads();
  if (t < 64) {
    float mm = -3.0e38f;
#pragma unroll
    for (int i = 0; i < 16; ++i) mm = fmaxf(mm, MsS[t][i]);
    float dd = 0.f;
#pragma unroll
    for (int i = 0; i < 16; ++i) dd += DsS[t][i] * __expf(MsS[t][i] - mm);
    Mx[(size_t)b * HW + x0 + t]   = mm;
    Dinv[(size_t)b * HW + x0 + t] = 1.0f / dd;
  }
}

__global__ __launch_bounds__(256) void k_out(
    const float* __restrict__ proj, const float* __restrict__ pem,
    const float* __restrict__ Mx, const float* __restrict__ Dinv,
    float* __restrict__ out) {
  __shared__ float As[KT][68];
  __shared__ float Bs[KT][68];
  __shared__ float E[64][68];
  const int y0 = blockIdx.x * 64;
  const int b  = blockIdx.y;
  const int t  = threadIdx.x;
  const int tx = t & 15, ty = t >> 4;
  const int kg = t >> 3, yg = t & 7;
  const float* pj = proj + (size_t)b * CO * HW;
  const float* pe = pem + (size_t)b * CO * HW;
  const float* Mb = Mx + (size_t)b * HW;
  const float* Db = Dinv + (size_t)b * HW;
  float acc[8][8] = {};
  for (int x0 = 0; x0 < HW; x0 += 64) {
    float s[4][4] = {};
    for (int c0 = 0; c0 < CO; c0 += KT) {
#pragma unroll
      for (int l = 0; l < 2; ++l) {
        int idx4 = t + l * 256;
        int c = idx4 >> 4, w4 = idx4 & 15;
        *(float4*)&As[c][w4 * 4] =
            *(const float4*)&pj[(size_t)(c0 + c) * HW + x0 + w4 * 4];
        *(float4*)&Bs[c][w4 * 4] =
            *(const float4*)&pe[(size_t)(c0 + c) * HW + y0 + w4 * 4];
      }
      __syncthreads();
#pragma unroll
      for (int c = 0; c < KT; ++c) {
        float4 a  = *(const float4*)&As[c][tx * 4];
        float4 bv = *(const float4*)&Bs[c][ty * 4];
        float av[4] = {a.x, a.y, a.z, a.w};
        float bb[4] = {bv.x, bv.y, bv.z, bv.w};
#pragma unroll
        for (int u = 0; u < 4; ++u)
#pragma unroll
          for (int v = 0; v < 4; ++v) s[u][v] += av[u] * bb[v];
      }
      __syncthreads();
    }
#pragma unroll
    for (int u = 0; u < 4; ++u) {
      int xr = x0 + tx * 4 + u;
      float mm = Mb[xr];
      float di = Db[xr];
      E[tx * 4 + u][ty * 4 + 0] = __expf(s[u][0] - mm) * di;
      E[tx * 4 + u][ty * 4 + 1] = __expf(s[u][1] - mm) * di;
      E[tx * 4 + u][ty * 4 + 2] = __expf(s[u][2] - mm) * di;
      E[tx * 4 + u][ty * 4 + 3] = __expf(s[u][3] - mm) * di;
    }
    __syncthreads();
    for (int xi = 0; xi < 64; xi += 4) {
      float4 p[8];
#pragma unroll
      for (int u = 0; u < 8; ++u)
        p[u] = *(const float4*)&pe[(size_t)(kg * 8 + u) * HW + x0 + xi];
#pragma unroll
      for (int j = 0; j < 4; ++j) {
        float4 e0 = *(const float4*)&E[xi + j][yg * 8];
        float4 e1 = *(const float4*)&E[xi + j][yg * 8 + 4];
        float evv[8] = {e0.x, e0.y, e0.z, e0.w, e1.x, e1.y, e1.z, e1.w};
#pragma unroll
        for (int u = 0; u < 8; ++u) {
          float a = (j == 0) ? p[u].x : (j == 1) ? p[u].y : (j == 2) ? p[u].z : p[u].w;
#pragma unroll
          for (int v = 0; v < 8; ++v) acc[u][v] += a * evv[v];
        }
      }
    }
    __syncthreads();
  }
#pragma unroll
  for (int u = 0; u < 8; ++u) {
    int k = kg * 8 + u;
    float4 r0, r1;
    r0.x = acc[u][0]; r0.y = acc[u][1]; r0.z = acc[u][2]; r0.w = acc[u][3];
    r1.x = acc[u][4]; r1.y = acc[u][5]; r1.z = acc[u][6]; r1.w = acc[u][7];
    float* ob = out + ((size_t)b * CO + k) * HW + y0 + yg * 8;
    *(float4*)&ob[0] = r0;
    *(float4*)&ob[4] = r1;
  }
}

// ===========================================================================
extern "C" void kernel_launch(void* const* d_in, const int* in_sizes, int n_in,
                              void* d_out, int out_size, void* d_ws, size_t ws_size,
                              hipStream_t stream) {
  const float* x    = (const float*)d_in[0];
  const float* pem  = (const float*)d_in[1];
  const float* W    = (const float*)d_in[2];
  const float* bias = (const float*)d_in[3];
  float* out = (float*)d_out;

  const size_t NS   = (size_t)BATCH * HW * CO;       // 8.39M
  const size_t HWB  = (size_t)BATCH * HW;            // 32768
  const size_t SNAP = (size_t)BATCH * NCHUNK * HW;   // 4.19M
  const size_t SEGN = (size_t)BATCH * NSEG * HW;     // 131072

  unsigned char* basep = (unsigned char*)d_ws;
  ushort_t* proj_hi  = (ushort_t*)basep;
  ushort_t* proj_lo  = proj_hi + NS;
  ushort_t* pem_t_hi = proj_lo + NS;
  ushort_t* pem_t_lo = pem_t_hi + NS;
  ushort_t* pem_h    = pem_t_lo + NS;
  float*    Mx       = (float*)(pem_h + NS);
  float*    Dinv     = Mx + HWB;
  float*    m_seg    = Dinv + HWB;
  float*    d_seg    = m_seg + SEGN;
  float*    m_snap   = d_seg + SEGN;
  _Float16* Ep       = (_Float16*)(m_snap + SNAP);

  const size_t base_need = 5 * NS * 2 + 2 * HWB * 4 + 2 * SEGN * 4 + SNAP * 4;
  const size_t e_full    = (size_t)BATCH * HW * HW * 2;   // 268.4 MB

  int rounds, nb;
  if (ws_size >= base_need + e_full)          { rounds = 1; nb = 8; }
  else if (ws_size >= base_need + e_full / 2) { rounds = 2; nb = 4; }
  else {
    // fp32 fallback
    float* proj = (float*)d_ws;
    float* Mx2  = proj + NS;
    float* Di2  = Mx2 + HWB;
    const size_t need = (NS + 2 * HWB) * sizeof(float);
    if (ws_size < need) return;
    k_proj <<<dim3(HW / 64, CO / 64, BATCH), 256, 0, stream>>>(x, W, bias, proj);
    k_stats<<<dim3(HW / 64, BATCH),          256, 0, stream>>>(proj, pem, Mx2, Di2);
    k_out  <<<dim3(HW / 64, BATCH),          256, 0, stream>>>(proj, pem, Mx2, Di2, out);
    return;
  }

  k_proj_split<<<dim3(HW / 64, CO / 64, BATCH), 256, 0, stream>>>(
      x, W, bias, proj_hi, proj_lo);
  k_tr_pem<<<dim3(HW / 64, CO / 64, BATCH), 256, 0, stream>>>(
      pem, pem_t_hi, pem_t_lo, pem_h);

  for (int rd = 0; rd < rounds; ++rd) {
    int b_base = rd * nb;
    k_pass1<<<nb * 128, 256, 0, stream>>>(proj_hi, proj_lo, pem_t_hi, pem_t_lo,
                                          Ep, m_snap, m_seg, d_seg, nb, b_base);
    k_red<<<nb * 16, 256, 0, stream>>>(m_seg, d_seg, Mx, Dinv, b_base);
    k_pass2<<<nb * 128, 256, 0, stream>>>(Ep, (const ushort_t*)pem_h, m_snap,
                                          Mx, Dinv, out, nb, b_base);
  }
}

// Round 5
// 452.705 us; speedup vs baseline: 2.2314x; 1.0602x over previous
//
#include <hip/hip_runtime.h>
#include <math.h>

#define BATCH 8
#define CIN 512
#define CO 256
#define HW 4096
#define KT 32
#define NCHUNK 128          // total y-chunks of 32
#define NSEG 4
#define SEGC (NCHUNK / NSEG)

typedef unsigned short ushort_t;
typedef unsigned int uint_t;
typedef __bf16 v8bf __attribute__((ext_vector_type(8)));
typedef _Float16 v8h __attribute__((ext_vector_type(8)));
typedef _Float16 v4h __attribute__((ext_vector_type(4)));
typedef float v4f __attribute__((ext_vector_type(4)));
typedef ushort_t u16x8 __attribute__((ext_vector_type(8)));

__device__ __forceinline__ ushort_t f2bf(float f) {
  uint_t u = __float_as_uint(f);
  u += 0x7FFFu + ((u >> 16) & 1u);
  return (ushort_t)(u >> 16);
}
__device__ __forceinline__ float bf2f(ushort_t h) {
  return __uint_as_float(((uint_t)h) << 16);
}
__device__ __forceinline__ v4f mfma16(v8bf a, v8bf b, v4f c) {
  return __builtin_amdgcn_mfma_f32_16x16x32_bf16(a, b, c, 0, 0, 0);
}
__device__ __forceinline__ v4f mfma16h(v8h a, v8h b, v4f c) {
  return __builtin_amdgcn_mfma_f32_16x16x32_f16(a, b, c, 0, 0, 0);
}
// pitch-512B tile, granule-XOR by (row&7)
__device__ __forceinline__ v8bf lds_frag(const unsigned char* base, int row, int cb) {
  uint4 v = *(const uint4*)(base + row * 512 + (((cb) ^ (row & 7)) << 4));
  return __builtin_bit_cast(v8bf, v);
}
// pitch-128B tile, granule-XOR by (row&7)
__device__ __forceinline__ v8bf lds_frag128(const unsigned char* base, int row, int cb) {
  uint4 v = *(const uint4*)(base + row * 128 + (((cb) ^ (row & 7)) << 4));
  return __builtin_bit_cast(v8bf, v);
}
// pitch-256B tile, granule-XOR by (row&15)
__device__ __forceinline__ v8h lds_frag_h16(const unsigned char* base, int row, int cb) {
  uint4 v = *(const uint4*)(base + row * 256 + (((cb) ^ (row & 15)) << 4));
  return __builtin_bit_cast(v8h, v);
}
__device__ __forceinline__ void gll16(const void* g, void* l) {
  __builtin_amdgcn_global_load_lds(
      (const __attribute__((address_space(1))) unsigned int*)g,
      (__attribute__((address_space(3))) unsigned int*)l, 16, 0, 0);
}

// ===========================================================================
// W [CO][CIN] fp32 -> w_hi/w_lo bf16 (row-major, same layout)
// ===========================================================================
__global__ __launch_bounds__(256) void k_w_split(
    const float* __restrict__ W, ushort_t* __restrict__ w_hi,
    ushort_t* __restrict__ w_lo) {
  int idx = blockIdx.x * 256 + threadIdx.x;   // 16384 threads, 8 elems each
  size_t off = (size_t)idx * 8;
  float4 v0 = *(const float4*)&W[off];
  float4 v1 = *(const float4*)&W[off + 4];
  float f[8] = {v0.x, v0.y, v0.z, v0.w, v1.x, v1.y, v1.z, v1.w};
  u16x8 h, l;
#pragma unroll
  for (int j = 0; j < 8; ++j) {
    ushort_t hh = f2bf(f[j]);
    h[j] = hh;
    l[j] = f2bf(f[j] - bf2f(hh));
  }
  *(u16x8*)&w_hi[off] = h;
  *(u16x8*)&w_lo[off] = l;
}

// ===========================================================================
// x [b][c][i] fp32 -> x_t [b][i][c] hi/lo bf16 (transposed, coalesced)
// ===========================================================================
__global__ __launch_bounds__(256) void k_tr_x(
    const float* __restrict__ x,
    ushort_t* __restrict__ xt_hi, ushort_t* __restrict__ xt_lo) {
  __shared__ float T[64][65];  // [c][i]
  const int i0 = blockIdx.x * 64;
  const int c0 = blockIdx.y * 64;
  const int b  = blockIdx.z;
  const int t  = threadIdx.x;
  const int cl = t >> 4;
  const int i4 = (t & 15) * 4;
#pragma unroll
  for (int r = 0; r < 4; ++r) {
    int c = c0 + r * 16 + cl;
    size_t off = ((size_t)b * CIN + c) * HW + i0 + i4;
    float4 v = *(const float4*)&x[off];
    T[r * 16 + cl][i4 + 0] = v.x;
    T[r * 16 + cl][i4 + 1] = v.y;
    T[r * 16 + cl][i4 + 2] = v.z;
    T[r * 16 + cl][i4 + 3] = v.w;
  }
  __syncthreads();
  {
    int il = t >> 2;
    int cs = (t & 3) * 16;
    u16x8 h0, h1, l0, l1;
#pragma unroll
    for (int j = 0; j < 8; ++j) {
      float f = T[cs + j][il];
      ushort_t h = f2bf(f);
      h0[j] = h;
      l0[j] = f2bf(f - bf2f(h));
    }
#pragma unroll
    for (int j = 0; j < 8; ++j) {
      float f = T[cs + 8 + j][il];
      ushort_t h = f2bf(f);
      h1[j] = h;
      l1[j] = f2bf(f - bf2f(h));
    }
    size_t ro = ((size_t)b * HW + i0 + il) * CIN + c0 + cs;
    *(u16x8*)&xt_hi[ro]     = h0;
    *(u16x8*)&xt_hi[ro + 8] = h1;
    *(u16x8*)&xt_lo[ro]     = l0;
    *(u16x8*)&xt_lo[ro + 8] = l1;
  }
}

// ===========================================================================
// proj_t[b][x][o] = bias[o] + sum_c x_t[b][x][c] * W[o][c]  via split-bf16 MFMA
// grid: 8b * 32xt * 2oh = 512 blocks. Block 256 thr. Tile 128x * 128o, BK=64.
// ===========================================================================
__global__ __launch_bounds__(256, 2) void k_proj_mfma(
    const ushort_t* __restrict__ xt_hi, const ushort_t* __restrict__ xt_lo,
    const ushort_t* __restrict__ w_hi, const ushort_t* __restrict__ w_lo,
    const float* __restrict__ bias,
    ushort_t* __restrict__ proj_hi, ushort_t* __restrict__ proj_lo) {
  __shared__ __align__(16) unsigned char L[4][128 * 128];  // xh,xl,wh,wl 16KB each
  const int bid = blockIdx.x;
  const int b = bid & 7;
  const int rest = bid >> 3;
  const int xt = rest & 31;
  const int oh = rest >> 5;
  const int x0 = xt * 128;
  const int t = threadIdx.x;
  const int lane = t & 63, wave = t >> 6;

  v4f acc[2][8];
#pragma unroll
  for (int xf = 0; xf < 2; ++xf)
#pragma unroll
    for (int of = 0; of < 8; ++of) acc[xf][of] = (v4f){0.f, 0.f, 0.f, 0.f};

  float bias_of[8];
#pragma unroll
  for (int of = 0; of < 8; ++of)
    bias_of[of] = bias[oh * 128 + of * 16 + (lane & 15)];

  for (int ch = 0; ch < 8; ++ch) {
    const int c0 = ch * 64;
#pragma unroll
    for (int i = 0; i < 4; ++i) {
      int G = i * 256 + t;
      int r = G >> 3, sl = G & 7;
      int cg = (sl ^ (r & 7)) << 3;
      size_t xsrc = ((size_t)b * HW + x0 + r) * CIN + c0 + cg;
      size_t wsrc = ((size_t)(oh * 128 + r)) * CIN + c0 + cg;
      unsigned lb = (unsigned)((i * 256 + wave * 64) << 4);
      gll16(&xt_hi[xsrc], &L[0][lb]);
      gll16(&xt_lo[xsrc], &L[1][lb]);
      gll16(&w_hi[wsrc],  &L[2][lb]);
      gll16(&w_lo[wsrc],  &L[3][lb]);
    }
    __syncthreads();
#pragma unroll
    for (int st = 0; st < 2; ++st) {
      int cb = st * 4 + (lane >> 4);
      v8bf ah0 = lds_frag128(L[0], wave * 32 + (lane & 15), cb);
      v8bf ah1 = lds_frag128(L[0], wave * 32 + 16 + (lane & 15), cb);
      v8bf al0 = lds_frag128(L[1], wave * 32 + (lane & 15), cb);
      v8bf al1 = lds_frag128(L[1], wave * 32 + 16 + (lane & 15), cb);
#pragma unroll
      for (int of = 0; of < 8; ++of) {
        v8bf bh = lds_frag128(L[2], of * 16 + (lane & 15), cb);
        v8bf bl = lds_frag128(L[3], of * 16 + (lane & 15), cb);
        acc[0][of] = mfma16(ah0, bh, acc[0][of]);
        acc[0][of] = mfma16(ah0, bl, acc[0][of]);
        acc[0][of] = mfma16(al0, bh, acc[0][of]);
        acc[1][of] = mfma16(ah1, bh, acc[1][of]);
        acc[1][of] = mfma16(ah1, bl, acc[1][of]);
        acc[1][of] = mfma16(al1, bh, acc[1][of]);
      }
    }
    __syncthreads();
  }

  // epilogue: bias + split -> LDS transpose -> coalesced store
  ushort_t* Th = (ushort_t*)&L[0][0];  // [128][128]
  ushort_t* Tl = (ushort_t*)&L[2][0];
#pragma unroll
  for (int xf = 0; xf < 2; ++xf)
#pragma unroll
    for (int of = 0; of < 8; ++of)
#pragma unroll
      for (int r = 0; r < 4; ++r) {
        int x_loc = wave * 32 + xf * 16 + (lane >> 4) * 4 + r;
        int o_loc = of * 16 + (lane & 15);
        float z = acc[xf][of][r] + bias_of[of];
        ushort_t hh = f2bf(z);
        Th[x_loc * 128 + o_loc] = hh;
        Tl[x_loc * 128 + o_loc] = f2bf(z - bf2f(hh));
      }
  __syncthreads();
  {
    int row = t >> 1, half = t & 1;
    size_t off = ((size_t)b * HW + x0 + row) * CO + oh * 128 + half * 64;
#pragma unroll
    for (int j = 0; j < 8; ++j)
      *(uint4*)&proj_hi[off + j * 8] = *(const uint4*)&Th[row * 128 + half * 64 + j * 8];
#pragma unroll
    for (int j = 0; j < 8; ++j)
      *(uint4*)&proj_lo[off + j * 8] = *(const uint4*)&Tl[row * 128 + half * 64 + j * 8];
  }
}

// ===========================================================================
// pem [b][c][y] fp32 -> pem_t[b][y][c] hi/lo bf16 (coalesced via LDS) and
//                       pem_h[b][c][y] f16 (coalesced direct)
// ===========================================================================
__global__ __launch_bounds__(256) void k_tr_pem(
    const float* __restrict__ pem,
    ushort_t* __restrict__ pem_t_hi, ushort_t* __restrict__ pem_t_lo,
    ushort_t* __restrict__ pem_h) {
  __shared__ float T[64][65];  // [c][y]
  const int y0 = blockIdx.x * 64;
  const int c0 = blockIdx.y * 64;
  const int b  = blockIdx.z;
  const int t  = threadIdx.x;
  const int cl = t >> 4;
  const int y4 = (t & 15) * 4;
#pragma unroll
  for (int r = 0; r < 4; ++r) {
    int c = c0 + r * 16 + cl;
    size_t off = ((size_t)b * CO + c) * HW + y0 + y4;
    float4 v = *(const float4*)&pem[off];
    ushort4 h;
    h.x = __builtin_bit_cast(ushort_t, (_Float16)v.x);
    h.y = __builtin_bit_cast(ushort_t, (_Float16)v.y);
    h.z = __builtin_bit_cast(ushort_t, (_Float16)v.z);
    h.w = __builtin_bit_cast(ushort_t, (_Float16)v.w);
    *(ushort4*)&pem_h[off] = h;
    T[r * 16 + cl][y4 + 0] = v.x;
    T[r * 16 + cl][y4 + 1] = v.y;
    T[r * 16 + cl][y4 + 2] = v.z;
    T[r * 16 + cl][y4 + 3] = v.w;
  }
  __syncthreads();
  {
    int yl = t >> 2;
    int cs = (t & 3) * 16;
    u16x8 h0, h1, l0, l1;
#pragma unroll
    for (int j = 0; j < 8; ++j) {
      float f = T[cs + j][yl];
      ushort_t h = f2bf(f);
      h0[j] = h;
      l0[j] = f2bf(f - bf2f(h));
    }
#pragma unroll
    for (int j = 0; j < 8; ++j) {
      float f = T[cs + 8 + j][yl];
      ushort_t h = f2bf(f);
      h1[j] = h;
      l1[j] = f2bf(f - bf2f(h));
    }
    size_t ro = ((size_t)b * HW + y0 + yl) * CO + c0 + cs;
    *(u16x8*)&pem_t_hi[ro]     = h0;
    *(u16x8*)&pem_t_hi[ro + 8] = h1;
    *(u16x8*)&pem_t_lo[ro]     = l0;
    *(u16x8*)&pem_t_lo[ro + 8] = l1;
  }
}

// ===========================================================================
// Pass 1: stats + E' materialization, y-segmented.
// grid: nb * 32(xt) * 4(seg). Block: 256 thr, x-tile 128, A in registers.
// Defer-max (THR=8): d per-lane, rescale only when row max grows > 8.
// E' flushed coalesced via LDS transpose -> Ep[bl*32+xt][y][128] f16.
// ===========================================================================
__global__ __launch_bounds__(256, 2) void k_pass1(
    const ushort_t* __restrict__ proj_hi, const ushort_t* __restrict__ proj_lo,
    const ushort_t* __restrict__ pem_t_hi, const ushort_t* __restrict__ pem_t_lo,
    _Float16* __restrict__ Ep, float* __restrict__ m_snap,
    float* __restrict__ m_seg, float* __restrict__ d_seg,
    int nb, int b_base) {
  __shared__ __align__(16) unsigned char pbuf[2][2][32 * 512];  // 64 KB
  __shared__ __align__(16) unsigned char Etr[2][32 * 256];      // 16 KB
  const int id = blockIdx.x;
  const int brel = id % nb;
  const int b = b_base + brel;
  const int rest = id / nb;
  const int xt = rest & 31;
  const int seg = rest >> 5;
  const int x0 = xt * 128;
  const int t = threadIdx.x;
  const int lane = t & 63, wave = t >> 6;
  const int xw = x0 + wave * 32;

  // A fragments resident in registers (proj hi/lo, K=256)
  v8bf Ah[2][8], Al[2][8];
#pragma unroll
  for (int xf = 0; xf < 2; ++xf) {
    const size_t ro =
        ((size_t)b * HW + xw + xf * 16 + (lane & 15)) * CO + (lane >> 4) * 8;
#pragma unroll
    for (int st = 0; st < 8; ++st) {
      Ah[xf][st] = __builtin_bit_cast(v8bf, *(const uint4*)&proj_hi[ro + st * 32]);
      Al[xf][st] = __builtin_bit_cast(v8bf, *(const uint4*)&proj_lo[ro + st * 32]);
    }
  }

  float m[2][4], d[2][4];
#pragma unroll
  for (int xf = 0; xf < 2; ++xf)
#pragma unroll
    for (int r = 0; r < 4; ++r) { m[xf][r] = -3.0e38f; d[xf][r] = 0.f; }

  auto stage = [&](int bufi, int tt) {
    const int yy0 = tt * 32;
#pragma unroll
    for (int i = 0; i < 4; ++i) {
      int G = i * 256 + t;
      int r = G >> 5, sl = G & 31;
      size_t so = ((size_t)b * HW + yy0 + r) * CO + ((sl ^ (r & 7)) << 3);
      unsigned lb = (unsigned)((i * 256 + wave * 64) << 4);
      gll16(&pem_t_hi[so], &pbuf[bufi][0][lb]);
      gll16(&pem_t_lo[so], &pbuf[bufi][1][lb]);
    }
  };

  const int tt0 = seg * SEGC;
  stage(0, tt0);
  __syncthreads();

  for (int tc = 0; tc < SEGC; ++tc) {
    const int tt = tt0 + tc;
    if (tc + 1 < SEGC) stage((tc + 1) & 1, tt + 1);

    const unsigned char* bh_p = pbuf[tc & 1][0];
    const unsigned char* bl_p = pbuf[tc & 1][1];
    v4f acc[2][2];
#pragma unroll
    for (int xf = 0; xf < 2; ++xf)
#pragma unroll
      for (int yc = 0; yc < 2; ++yc) acc[xf][yc] = (v4f){0.f, 0.f, 0.f, 0.f};

#pragma unroll
    for (int st = 0; st < 8; ++st) {
#pragma unroll
      for (int yc = 0; yc < 2; ++yc) {
        int row = yc * 16 + (lane & 15);
        int cb  = st * 4 + (lane >> 4);
        v8bf bh = lds_frag(bh_p, row, cb);
        v8bf bv = lds_frag(bl_p, row, cb);
        acc[0][yc] = mfma16(Ah[0][st], bh, acc[0][yc]);
        acc[1][yc] = mfma16(Ah[1][st], bh, acc[1][yc]);
        acc[0][yc] = mfma16(Al[0][st], bh, acc[0][yc]);
        acc[1][yc] = mfma16(Al[1][st], bh, acc[1][yc]);
        acc[0][yc] = mfma16(Ah[0][st], bv, acc[0][yc]);
        acc[1][yc] = mfma16(Ah[1][st], bv, acc[1][yc]);
      }
    }

    // ---- defer-max stats + E' ----
#pragma unroll
    for (int xf = 0; xf < 2; ++xf) {
      float mx8 = fmaxf(fmaxf(fmaxf(acc[xf][0][0], acc[xf][0][1]),
                              fmaxf(acc[xf][0][2], acc[xf][0][3])),
                        fmaxf(fmaxf(acc[xf][1][0], acc[xf][1][1]),
                              fmaxf(acc[xf][1][2], acc[xf][1][3])));
      float minm = fminf(fminf(m[xf][0], m[xf][1]), fminf(m[xf][2], m[xf][3]));
      if (__any(mx8 > minm + 8.0f)) {
#pragma unroll
        for (int r = 0; r < 4; ++r) {
          float rm = fmaxf(acc[xf][0][r], acc[xf][1][r]);
          rm = fmaxf(rm, __shfl_xor(rm, 1));
          rm = fmaxf(rm, __shfl_xor(rm, 2));
          rm = fmaxf(rm, __shfl_xor(rm, 4));
          rm = fmaxf(rm, __shfl_xor(rm, 8));
          float mn = fmaxf(m[xf][r], rm);
          d[xf][r] *= __expf(m[xf][r] - mn);
          m[xf][r] = mn;
        }
      }
      v4h p0, p1;
#pragma unroll
      for (int r = 0; r < 4; ++r) {
        float e0 = __expf(acc[xf][0][r] - m[xf][r]);
        float e1 = __expf(acc[xf][1][r] - m[xf][r]);
        d[xf][r] += e0 + e1;
        p0[r] = (_Float16)e0;
        p1[r] = (_Float16)e1;
      }
      {
        int gx = (wave * 32 + xf * 16 + (lane >> 4) * 4) >> 3;
        int half = (lane >> 4) & 1;
        int y0l = lane & 15, y1l = 16 + (lane & 15);
        *(uint2*)&Etr[tc & 1][y0l * 256 + ((gx ^ (y0l & 15)) << 4) + half * 8] =
            __builtin_bit_cast(uint2, p0);
        *(uint2*)&Etr[tc & 1][y1l * 256 + ((gx ^ (y1l & 15)) << 4) + half * 8] =
            __builtin_bit_cast(uint2, p1);
      }
      if ((lane & 15) == 0) {
        *(float4*)&m_snap[((size_t)b * NCHUNK + tt) * HW + xw + xf * 16 +
                          (lane >> 4) * 4] =
            make_float4(m[xf][0], m[xf][1], m[xf][2], m[xf][3]);
      }
    }
    __syncthreads();  // Etr ready; gll16 drained; pbuf[cur] reads done
    // ---- flush Etr -> Ep (coalesced 32B per thread) ----
    {
      int yr = t >> 3;
      int g0 = (t & 7) * 2, g1 = g0 + 1;
      uint4 v0 = *(uint4*)&Etr[tc & 1][yr * 256 + ((g0 ^ (yr & 15)) << 4)];
      uint4 v1 = *(uint4*)&Etr[tc & 1][yr * 256 + ((g1 ^ (yr & 15)) << 4)];
      size_t go = (((size_t)(brel * 32 + xt)) * HW + (size_t)tt * 32 + yr) * 128;
      *(uint4*)&Ep[go + g0 * 8] = v0;
      *(uint4*)&Ep[go + g1 * 8] = v1;
    }
  }

  // ---- segment (m, d) out ----
#pragma unroll
  for (int xf = 0; xf < 2; ++xf) {
    float dv[4];
#pragma unroll
    for (int r = 0; r < 4; ++r) {
      float v = d[xf][r];
      v += __shfl_xor(v, 1);
      v += __shfl_xor(v, 2);
      v += __shfl_xor(v, 4);
      v += __shfl_xor(v, 8);
      dv[r] = v;
    }
    if ((lane & 15) == 0) {
      size_t o = ((size_t)(b * NSEG + seg)) * HW + xw + xf * 16 + (lane >> 4) * 4;
      *(float4*)&m_seg[o] = make_float4(m[xf][0], m[xf][1], m[xf][2], m[xf][3]);
      *(float4*)&d_seg[o] = make_float4(dv[0], dv[1], dv[2], dv[3]);
    }
  }
}

// ===========================================================================
// Merge segments -> Mx, Dinv
// ===========================================================================
__global__ __launch_bounds__(256) void k_red(
    const float* __restrict__ m_seg, const float* __restrict__ d_seg,
    float* __restrict__ Mx, float* __restrict__ Dinv, int b_base) {
  int idx = blockIdx.x * 256 + threadIdx.x;
  int b = b_base + (idx >> 12);
  int xx = idx & 4095;
  float ms[NSEG], ds[NSEG];
  float mm = -3.0e38f;
#pragma unroll
  for (int s = 0; s < NSEG; ++s) {
    ms[s] = m_seg[((size_t)(b * NSEG + s)) * HW + xx];
    ds[s] = d_seg[((size_t)(b * NSEG + s)) * HW + xx];
    mm = fmaxf(mm, ms[s]);
  }
  float dd = 0.f;
#pragma unroll
  for (int s = 0; s < NSEG; ++s) dd += ds[s] * __expf(ms[s] - mm);
  Mx[(size_t)b * HW + xx]   = mm;
  Dinv[(size_t)b * HW + xx] = 1.0f / dd;
}

// ===========================================================================
// Pass 2: out[b,k,y] = sum_x pem[k,x] * s(tt(y),x) * E'[x,y]  (f16 MFMA)
// ===========================================================================
__global__ __launch_bounds__(256, 2) void k_pass2(
    const _Float16* __restrict__ Ep, const ushort_t* __restrict__ pem_h_u,
    const float* __restrict__ m_snap, const float* __restrict__ Mx,
    const float* __restrict__ Dinv, float* __restrict__ out,
    int nb, int b_base) {
  __shared__ __align__(16) unsigned char pml[128 * 256];   // 32 KB
  __shared__ __align__(16) unsigned char el[2][64 * 256];  // 32 KB
  __shared__ __align__(16) _Float16 slds[2][256];
  const int id = blockIdx.x;
  const int brel = id % nb;
  const int b = b_base + brel;
  const int rest = id / nb;
  const int kh = rest & 1;
  const int yt = rest >> 1;
  const int y0 = yt * 64;
  const int t = threadIdx.x;
  const int lane = t & 63, wave = t >> 6;
  const _Float16* pem_h = (const _Float16*)pem_h_u;

  v4f oacc[2][4];
#pragma unroll
  for (int kf = 0; kf < 2; ++kf)
#pragma unroll
    for (int yf = 0; yf < 4; ++yf) oacc[kf][yf] = (v4f){0.f, 0.f, 0.f, 0.f};

  auto stage_pml = [&](int xt) {
#pragma unroll
    for (int i = 0; i < 8; ++i) {
      int G = i * 256 + t;
      int r = G >> 4, sl = G & 15;
      size_t so = ((size_t)b * CO + kh * 128 + r) * HW + xt * 128 +
                  ((sl ^ (r & 15)) << 3);
      gll16(&pem_h[so], &pml[(unsigned)((i * 256 + wave * 64) << 4)]);
    }
  };
  auto load_el = [&](int xt, uint4* ev) {
    const size_t slab = ((size_t)(brel * 32 + xt)) * HW * 128;
#pragma unroll
    for (int i = 0; i < 4; ++i) {
      int G = i * 256 + t;
      ev[i] = *(const uint4*)&Ep[slab + (size_t)(y0 + (G >> 4)) * 128 +
                                 (G & 15) * 8];
    }
  };
  auto comp_s = [&](int bufi, int xt) {
    int ttrel = t >> 7, xr = t & 127;
    int ttg = (y0 >> 5) + ttrel;
    size_t xg = (size_t)xt * 128 + xr;
    float ms = m_snap[((size_t)b * NCHUNK + ttg) * HW + xg];
    float s = __expf(ms - Mx[(size_t)b * HW + xg]) * Dinv[(size_t)b * HW + xg];
    slds[bufi][ttrel * 128 + xr] = (_Float16)s;
  };
  auto write_el = [&](int bufi, const uint4* ev) {
#pragma unroll
    for (int i = 0; i < 4; ++i) {
      int G = i * 256 + t;
      int yl = G >> 4, sl = G & 15;
      v8h e = __builtin_bit_cast(v8h, ev[i]);
      v8h s = *(const v8h*)&slds[bufi][(yl >> 5) * 128 + sl * 8];
      e = e * s;
      *(uint4*)&el[bufi][yl * 256 + ((sl ^ (yl & 15)) << 4)] =
          __builtin_bit_cast(uint4, e);
    }
  };

  uint4 ev[4];
  // prologue
  comp_s(0, 0);
  load_el(0, ev);
  stage_pml(0);
  __syncthreads();          // slds[0] visible, pml(0) ready
  write_el(0, ev);
  comp_s(1, 1);
  __syncthreads();          // el[0], slds[1] visible

  for (int xt = 0; xt < 32; ++xt) {
    const int cur = xt & 1, nxt = cur ^ 1;
    if (xt + 1 < 32) load_el(xt + 1, ev);
    // ---- MFMA ----
#pragma unroll
    for (int st = 0; st < 4; ++st) {
      int cb = st * 4 + (lane >> 4);
      v8h af0 = lds_frag_h16(pml, wave * 32 + (lane & 15), cb);
      v8h af1 = lds_frag_h16(pml, wave * 32 + 16 + (lane & 15), cb);
      v8h bf0 = lds_frag_h16(el[cur], 0 + (lane & 15), cb);
      v8h bf1 = lds_frag_h16(el[cur], 16 + (lane & 15), cb);
      v8h bf2 = lds_frag_h16(el[cur], 32 + (lane & 15), cb);
      v8h bf3 = lds_frag_h16(el[cur], 48 + (lane & 15), cb);
      oacc[0][0] = mfma16h(af0, bf0, oacc[0][0]);
      oacc[0][1] = mfma16h(af0, bf1, oacc[0][1]);
      oacc[0][2] = mfma16h(af0, bf2, oacc[0][2]);
      oacc[0][3] = mfma16h(af0, bf3, oacc[0][3]);
      oacc[1][0] = mfma16h(af1, bf0, oacc[1][0]);
      oacc[1][1] = mfma16h(af1, bf1, oacc[1][1]);
      oacc[1][2] = mfma16h(af1, bf2, oacc[1][2]);
      oacc[1][3] = mfma16h(af1, bf3, oacc[1][3]);
    }
    __syncthreads();        // pml/el[cur] reads done by all waves
    if (xt + 1 < 32) {
      stage_pml(xt + 1);
      write_el(nxt, ev);
      if (xt + 2 < 32) comp_s(cur, xt + 2);
    }
    __syncthreads();        // gll16 drained; el[nxt]/slds visible
  }

#pragma unroll
  for (int kf = 0; kf < 2; ++kf)
#pragma unroll
    for (int yf = 0; yf < 4; ++yf)
#pragma unroll
      for (int r = 0; r < 4; ++r) {
        int k = kh * 128 + wave * 32 + kf * 16 + (lane >> 4) * 4 + r;
        int y = y0 + yf * 16 + (lane & 15);
        out[((size_t)b * CO + k) * HW + y] = oacc[kf][yf][r];
      }
}

// ===========================================================================
// fp32 fallback path (used only if ws is too small)
// ===========================================================================
__global__ __launch_bounds__(256) void k_proj(
    const float* __restrict__ x, const float* __restrict__ W,
    const float* __restrict__ bias, float* __restrict__ proj) {
  __shared__ float As[KT][68];
  __shared__ float Bs[KT][68];
  const int i0 = blockIdx.x * 64;
  const int o0 = blockIdx.y * 64;
  const int b  = blockIdx.z;
  const int t  = threadIdx.x;
  const int tx = t & 15, ty = t >> 4;
  const float* xb = x + (size_t)b * CIN * HW;
  float acc[4][4] = {};
  for (int c0 = 0; c0 < CIN; c0 += KT) {
#pragma unroll
    for (int l = 0; l < 8; ++l) {
      int idx = t + l * 256;
      int o = idx >> 5;
      int c = idx & 31;
      As[c][o] = W[(size_t)(o0 + o) * CIN + c0 + c];
    }
#pragma unroll
    for (int l = 0; l < 2; ++l) {
      int idx4 = t + l * 256;
      int c = idx4 >> 4;
      int i4 = idx4 & 15;
      *(float4*)&Bs[c][i4 * 4] =
          *(const float4*)&xb[(size_t)(c0 + c) * HW + i0 + i4 * 4];
    }
    __syncthreads();
#pragma unroll
    for (int c = 0; c < KT; ++c) {
      float4 a  = *(const float4*)&As[c][tx * 4];
      float4 bv = *(const float4*)&Bs[c][ty * 4];
      float av[4] = {a.x, a.y, a.z, a.w};
      float bb[4] = {bv.x, bv.y, bv.z, bv.w};
#pragma unroll
      for (int u = 0; u < 4; ++u)
#pragma unroll
        for (int v = 0; v < 4; ++v) acc[u][v] += av[u] * bb[v];
    }
    __syncthreads();
  }
  float* pbout = proj + (size_t)b * CO * HW;
#pragma unroll
  for (int u = 0; u < 4; ++u) {
    int o = o0 + tx * 4 + u;
    float bsv = bias[o];
    float4 r;
    r.x = acc[u][0] + bsv; r.y = acc[u][1] + bsv;
    r.z = acc[u][2] + bsv; r.w = acc[u][3] + bsv;
    *(float4*)&pbout[(size_t)o * HW + i0 + ty * 4] = r;
  }
}

__global__ __launch_bounds__(256) void k_stats(
    const float* __restrict__ proj, const float* __restrict__ pem,
    float* __restrict__ Mx, float* __restrict__ Dinv) {
  __shared__ float As[KT][68];
  __shared__ float Bs[KT][68];
  __shared__ float MsS[64][17];
  __shared__ float DsS[64][17];
  const int x0 = blockIdx.x * 64;
  const int b  = blockIdx.y;
  const int t  = threadIdx.x;
  const int tx = t & 15, ty = t >> 4;
  const float* pj = proj + (size_t)b * CO * HW;
  const float* pe = pem + (size_t)b * CO * HW;
  float m[4], d[4];
#pragma unroll
  for (int u = 0; u < 4; ++u) { m[u] = -3.0e38f; d[u] = 0.f; }
  for (int y0 = 0; y0 < HW; y0 += 64) {
    float s[4][4] = {};
    for (int c0 = 0; c0 < CO; c0 += KT) {
#pragma unroll
      for (int l = 0; l < 2; ++l) {
        int idx4 = t + l * 256;
        int c = idx4 >> 4, w4 = idx4 & 15;
        *(float4*)&As[c][w4 * 4] =
            *(const float4*)&pj[(size_t)(c0 + c) * HW + x0 + w4 * 4];
        *(float4*)&Bs[c][w4 * 4] =
            *(const float4*)&pe[(size_t)(c0 + c) * HW + y0 + w4 * 4];
      }
      __syncthreads();
#pragma unroll
      for (int c = 0; c < KT; ++c) {
        float4 a  = *(const float4*)&As[c][tx * 4];
        float4 bv = *(const float4*)&Bs[c][ty * 4];
        float av[4] = {a.x, a.y, a.z, a.w};
        float bb[4] = {bv.x, bv.y, bv.z, bv.w};
#pragma unroll
        for (int u = 0; u < 4; ++u)
#pragma unroll
          for (int v = 0; v < 4; ++v) s[u][v] += av[u] * bb[v];
      }
      __syncthreads();
    }
#pragma unroll
    for (int u = 0; u < 4; ++u) {
      float mv = fmaxf(fmaxf(s[u][0], s[u][1]), fmaxf(s[u][2], s[u][3]));
      if (mv > m[u]) { d[u] *= __expf(m[u] - mv); m[u] = mv; }
      d[u] += __expf(s[u][0] - m[u]) + __expf(s[u][1] - m[u]) +
              __expf(s[u][2] - m[u]) + __expf(s[u][3] - m[u]);
    }
  }
#pragma unroll
  for (int u = 0; u < 4; ++u) { MsS[tx * 4 + u][ty] = m[u]; DsS[tx * 4 + u][ty] = d[u]; }
  __syncthreads();
  if (t < 64) {
    float mm = -3.0e38f;
#pragma unroll
    for (int i = 0; i < 16; ++i) mm = fmaxf(mm, MsS[t][i]);
    float dd = 0.f;
#pragma unroll
    for (int i = 0; i < 16; ++i) dd += DsS[t][i] * __expf(MsS[t][i] - mm);
    Mx[(size_t)b * HW + x0 + t]   = mm;
    Dinv[(size_t)b * HW + x0 + t] = 1.0f / dd;
  }
}

__global__ __launch_bounds__(256) void k_out(
    const float* __restrict__ proj, const float* __restrict__ pem,
    const float* __restrict__ Mx, const float* __restrict__ Dinv,
    float* __restrict__ out) {
  __shared__ float As[KT][68];
  __shared__ float Bs[KT][68];
  __shared__ float E[64][68];
  const int y0 = blockIdx.x * 64;
  const int b  = blockIdx.y;
  const int t  = threadIdx.x;
  const int tx = t & 15, ty = t >> 4;
  const int kg = t >> 3, yg = t & 7;
  const float* pj = proj + (size_t)b * CO * HW;
  const float* pe = pem + (size_t)b * CO * HW;
  const float* Mb = Mx + (size_t)b * HW;
  const float* Db = Dinv + (size_t)b * HW;
  float acc[8][8] = {};
  for (int x0 = 0; x0 < HW; x0 += 64) {
    float s[4][4] = {};
    for (int c0 = 0; c0 < CO; c0 += KT) {
#pragma unroll
      for (int l = 0; l < 2; ++l) {
        int idx4 = t + l * 256;
        int c = idx4 >> 4, w4 = idx4 & 15;
        *(float4*)&As[c][w4 * 4] =
            *(const float4*)&pj[(size_t)(c0 + c) * HW + x0 + w4 * 4];
        *(float4*)&Bs[c][w4 * 4] =
            *(const float4*)&pe[(size_t)(c0 + c) * HW + y0 + w4 * 4];
      }
      __syncthreads();
#pragma unroll
      for (int c = 0; c < KT; ++c) {
        float4 a  = *(const float4*)&As[c][tx * 4];
        float4 bv = *(const float4*)&Bs[c][ty * 4];
        float av[4] = {a.x, a.y, a.z, a.w};
        float bb[4] = {bv.x, bv.y, bv.z, bv.w};
#pragma unroll
        for (int u = 0; u < 4; ++u)
#pragma unroll
          for (int v = 0; v < 4; ++v) s[u][v] += av[u] * bb[v];
      }
      __syncthreads();
    }
#pragma unroll
    for (int u = 0; u < 4; ++u) {
      int xr = x0 + tx * 4 + u;
      float mm = Mb[xr];
      float di = Db[xr];
      E[tx * 4 + u][ty * 4 + 0] = __expf(s[u][0] - mm) * di;
      E[tx * 4 + u][ty * 4 + 1] = __expf(s[u][1] - mm) * di;
      E[tx * 4 + u][ty * 4 + 2] = __expf(s[u][2] - mm) * di;
      E[tx * 4 + u][ty * 4 + 3] = __expf(s[u][3] - mm) * di;
    }
    __syncthreads();
    for (int xi = 0; xi < 64; xi += 4) {
      float4 p[8];
#pragma unroll
      for (int u = 0; u < 8; ++u)
        p[u] = *(const float4*)&pe[(size_t)(kg * 8 + u) * HW + x0 + xi];
#pragma unroll
      for (int j = 0; j < 4; ++j) {
        float4 e0 = *(const float4*)&E[xi + j][yg * 8];
        float4 e1 = *(const float4*)&E[xi + j][yg * 8 + 4];
        float evv[8] = {e0.x, e0.y, e0.z, e0.w, e1.x, e1.y, e1.z, e1.w};
#pragma unroll
        for (int u = 0; u < 8; ++u) {
          float a = (j == 0) ? p[u].x : (j == 1) ? p[u].y : (j == 2) ? p[u].z : p[u].w;
#pragma unroll
          for (int v = 0; v < 8; ++v) acc[u][v] += a * evv[v];
        }
      }
    }
    __syncthreads();
  }
#pragma unroll
  for (int u = 0; u < 8; ++u) {
    int k = kg * 8 + u;
    float4 r0, r1;
    r0.x = acc[u][0]; r0.y = acc[u][1]; r0.z = acc[u][2]; r0.w = acc[u][3];
    r1.x = acc[u][4]; r1.y = acc[u][5]; r1.z = acc[u][6]; r1.w = acc[u][7];
    float* ob = out + ((size_t)b * CO + k) * HW + y0 + yg * 8;
    *(float4*)&ob[0] = r0;
    *(float4*)&ob[4] = r1;
  }
}

// ===========================================================================
extern "C" void kernel_launch(void* const* d_in, const int* in_sizes, int n_in,
                              void* d_out, int out_size, void* d_ws, size_t ws_size,
                              hipStream_t stream) {
  const float* x    = (const float*)d_in[0];
  const float* pem  = (const float*)d_in[1];
  const float* W    = (const float*)d_in[2];
  const float* bias = (const float*)d_in[3];
  float* out = (float*)d_out;

  const size_t NS   = (size_t)BATCH * HW * CO;       // 8.39M
  const size_t NS2  = (size_t)BATCH * HW * CIN;      // 16.78M
  const size_t HWB  = (size_t)BATCH * HW;            // 32768
  const size_t SNAP = (size_t)BATCH * NCHUNK * HW;   // 4.19M
  const size_t SEGN = (size_t)BATCH * NSEG * HW;     // 131072

  unsigned char* basep = (unsigned char*)d_ws;
  ushort_t* proj_hi  = (ushort_t*)basep;
  ushort_t* proj_lo  = proj_hi + NS;
  ushort_t* pem_t_hi = proj_lo + NS;
  ushort_t* pem_t_lo = pem_t_hi + NS;
  ushort_t* pem_h    = pem_t_lo + NS;
  float*    Mx       = (float*)(pem_h + NS);
  float*    Dinv     = Mx + HWB;
  float*    m_seg    = Dinv + HWB;
  float*    d_seg    = m_seg + SEGN;
  float*    m_snap   = d_seg + SEGN;
  _Float16* Ep       = (_Float16*)(m_snap + SNAP);

  // x_t / W-split live inside the Ep region (consumed before pass1 writes Ep)
  ushort_t* xt_hi = (ushort_t*)Ep;
  ushort_t* xt_lo = xt_hi + NS2;
  ushort_t* w_hi  = xt_lo + NS2;
  ushort_t* w_lo  = w_hi + (size_t)CO * CIN;

  const size_t base_need = 5 * NS * 2 + 2 * HWB * 4 + 2 * SEGN * 4 + SNAP * 4;
  const size_t e_full    = (size_t)BATCH * HW * HW * 2;   // 268.4 MB

  int rounds, nb;
  if (ws_size >= base_need + e_full)          { rounds = 1; nb = 8; }
  else if (ws_size >= base_need + e_full / 2) { rounds = 2; nb = 4; }
  else {
    // fp32 fallback
    float* proj = (float*)d_ws;
    float* Mx2  = proj + NS;
    float* Di2  = Mx2 + HWB;
    const size_t need = (NS + 2 * HWB) * sizeof(float);
    if (ws_size < need) return;
    k_proj <<<dim3(HW / 64, CO / 64, BATCH), 256, 0, stream>>>(x, W, bias, proj);
    k_stats<<<dim3(HW / 64, BATCH),          256, 0, stream>>>(proj, pem, Mx2, Di2);
    k_out  <<<dim3(HW / 64, BATCH),          256, 0, stream>>>(proj, pem, Mx2, Di2, out);
    return;
  }

  k_w_split<<<64, 256, 0, stream>>>(W, w_hi, w_lo);
  k_tr_x<<<dim3(HW / 64, CIN / 64, BATCH), 256, 0, stream>>>(x, xt_hi, xt_lo);
  k_proj_mfma<<<512, 256, 0, stream>>>(xt_hi, xt_lo, w_hi, w_lo, bias,
                                       proj_hi, proj_lo);
  k_tr_pem<<<dim3(HW / 64, CO / 64, BATCH), 256, 0, stream>>>(
      pem, pem_t_hi, pem_t_lo, pem_h);

  for (int rd = 0; rd < rounds; ++rd) {
    int b_base = rd * nb;
    k_pass1<<<nb * 128, 256, 0, stream>>>(proj_hi, proj_lo, pem_t_hi, pem_t_lo,
                                          Ep, m_snap, m_seg, d_seg, nb, b_base);
    k_red<<<nb * 16, 256, 0, stream>>>(m_seg, d_seg, Mx, Dinv, b_base);
    k_pass2<<<nb * 128, 256, 0, stream>>>(Ep, (const ushort_t*)pem_h, m_snap,
                                          Mx, Dinv, out, nb, b_base);
  }
}

// Round 6
// 360.707 us; speedup vs baseline: 2.8005x; 1.2550x over previous
//
#include <hip/hip_runtime.h>
#include <math.h>

#define BATCH 8
#define CIN 512
#define CO 256
#define HW 4096
#define KT 32
#define NCHUNK 128          // total y-chunks of 32
#define NSEG 4
#define SEGC (NCHUNK / NSEG)

typedef unsigned short ushort_t;
typedef unsigned int uint_t;
typedef __bf16 v8bf __attribute__((ext_vector_type(8)));
typedef _Float16 v8h __attribute__((ext_vector_type(8)));
typedef _Float16 v4h __attribute__((ext_vector_type(4)));
typedef float v4f __attribute__((ext_vector_type(4)));
typedef ushort_t u16x8 __attribute__((ext_vector_type(8)));

__device__ __forceinline__ ushort_t f2bf(float f) {
  uint_t u = __float_as_uint(f);
  u += 0x7FFFu + ((u >> 16) & 1u);
  return (ushort_t)(u >> 16);
}
__device__ __forceinline__ float bf2f(ushort_t h) {
  return __uint_as_float(((uint_t)h) << 16);
}
__device__ __forceinline__ ushort_t f2h(float f) {
  return __builtin_bit_cast(ushort_t, (_Float16)f);
}
__device__ __forceinline__ v4f mfma16(v8bf a, v8bf b, v4f c) {
  return __builtin_amdgcn_mfma_f32_16x16x32_bf16(a, b, c, 0, 0, 0);
}
__device__ __forceinline__ v4f mfma16h(v8h a, v8h b, v4f c) {
  return __builtin_amdgcn_mfma_f32_16x16x32_f16(a, b, c, 0, 0, 0);
}
// pitch-512B tile (f16), granule-XOR by (row&7)
__device__ __forceinline__ v8h lds_frag_h512(const unsigned char* base, int row, int cb) {
  uint4 v = *(const uint4*)(base + row * 512 + (((cb) ^ (row & 7)) << 4));
  return __builtin_bit_cast(v8h, v);
}
// pitch-128B tile (bf16), granule-XOR by (row&7)
__device__ __forceinline__ v8bf lds_frag128(const unsigned char* base, int row, int cb) {
  uint4 v = *(const uint4*)(base + row * 128 + (((cb) ^ (row & 7)) << 4));
  return __builtin_bit_cast(v8bf, v);
}
// pitch-256B tile (f16), granule-XOR by (row&15)
__device__ __forceinline__ v8h lds_frag_h16(const unsigned char* base, int row, int cb) {
  uint4 v = *(const uint4*)(base + row * 256 + (((cb) ^ (row & 15)) << 4));
  return __builtin_bit_cast(v8h, v);
}
__device__ __forceinline__ void gll16(const void* g, void* l) {
  __builtin_amdgcn_global_load_lds(
      (const __attribute__((address_space(1))) unsigned int*)g,
      (__attribute__((address_space(3))) unsigned int*)l, 16, 0, 0);
}

// ===========================================================================
// W [CO][CIN] fp32 -> w_hi/w_lo bf16 (row-major, same layout)
// ===========================================================================
__global__ __launch_bounds__(256) void k_w_split(
    const float* __restrict__ W, ushort_t* __restrict__ w_hi,
    ushort_t* __restrict__ w_lo) {
  int idx = blockIdx.x * 256 + threadIdx.x;
  size_t off = (size_t)idx * 8;
  float4 v0 = *(const float4*)&W[off];
  float4 v1 = *(const float4*)&W[off + 4];
  float f[8] = {v0.x, v0.y, v0.z, v0.w, v1.x, v1.y, v1.z, v1.w};
  u16x8 h, l;
#pragma unroll
  for (int j = 0; j < 8; ++j) {
    ushort_t hh = f2bf(f[j]);
    h[j] = hh;
    l[j] = f2bf(f[j] - bf2f(hh));
  }
  *(u16x8*)&w_hi[off] = h;
  *(u16x8*)&w_lo[off] = l;
}

// ===========================================================================
// x [b][c][i] fp32 -> x_t [b][i][c] hi/lo bf16 (transposed, coalesced)
// ===========================================================================
__global__ __launch_bounds__(256) void k_tr_x(
    const float* __restrict__ x,
    ushort_t* __restrict__ xt_hi, ushort_t* __restrict__ xt_lo) {
  __shared__ float T[64][65];  // [c][i]
  const int i0 = blockIdx.x * 64;
  const int c0 = blockIdx.y * 64;
  const int b  = blockIdx.z;
  const int t  = threadIdx.x;
  const int cl = t >> 4;
  const int i4 = (t & 15) * 4;
#pragma unroll
  for (int r = 0; r < 4; ++r) {
    int c = c0 + r * 16 + cl;
    size_t off = ((size_t)b * CIN + c) * HW + i0 + i4;
    float4 v = *(const float4*)&x[off];
    T[r * 16 + cl][i4 + 0] = v.x;
    T[r * 16 + cl][i4 + 1] = v.y;
    T[r * 16 + cl][i4 + 2] = v.z;
    T[r * 16 + cl][i4 + 3] = v.w;
  }
  __syncthreads();
  {
    int il = t >> 2;
    int cs = (t & 3) * 16;
    u16x8 h0, h1, l0, l1;
#pragma unroll
    for (int j = 0; j < 8; ++j) {
      float f = T[cs + j][il];
      ushort_t h = f2bf(f);
      h0[j] = h;
      l0[j] = f2bf(f - bf2f(h));
    }
#pragma unroll
    for (int j = 0; j < 8; ++j) {
      float f = T[cs + 8 + j][il];
      ushort_t h = f2bf(f);
      h1[j] = h;
      l1[j] = f2bf(f - bf2f(h));
    }
    size_t ro = ((size_t)b * HW + i0 + il) * CIN + c0 + cs;
    *(u16x8*)&xt_hi[ro]     = h0;
    *(u16x8*)&xt_hi[ro + 8] = h1;
    *(u16x8*)&xt_lo[ro]     = l0;
    *(u16x8*)&xt_lo[ro + 8] = l1;
  }
}

// ===========================================================================
// proj_t[b][x][o] = bias[o] + sum_c x_t[b][x][c] * W[o][c]  (split-bf16 MFMA)
// output: proj_h f16. grid: 8b*32xt*2oh = 512 blocks, 256 thr.
// ===========================================================================
__global__ __launch_bounds__(256, 2) void k_proj_mfma(
    const ushort_t* __restrict__ xt_hi, const ushort_t* __restrict__ xt_lo,
    const ushort_t* __restrict__ w_hi, const ushort_t* __restrict__ w_lo,
    const float* __restrict__ bias, ushort_t* __restrict__ proj_h) {
  __shared__ __align__(16) unsigned char L[4][128 * 128];  // xh,xl,wh,wl 16KB each
  const int bid = blockIdx.x;
  const int b = bid & 7;
  const int rest = bid >> 3;
  const int xt = rest & 31;
  const int oh = rest >> 5;
  const int x0 = xt * 128;
  const int t = threadIdx.x;
  const int lane = t & 63, wave = t >> 6;

  v4f acc[2][8];
#pragma unroll
  for (int xf = 0; xf < 2; ++xf)
#pragma unroll
    for (int of = 0; of < 8; ++of) acc[xf][of] = (v4f){0.f, 0.f, 0.f, 0.f};

  float bias_of[8];
#pragma unroll
  for (int of = 0; of < 8; ++of)
    bias_of[of] = bias[oh * 128 + of * 16 + (lane & 15)];

  for (int ch = 0; ch < 8; ++ch) {
    const int c0 = ch * 64;
#pragma unroll
    for (int i = 0; i < 4; ++i) {
      int G = i * 256 + t;
      int r = G >> 3, sl = G & 7;
      int cg = (sl ^ (r & 7)) << 3;
      size_t xsrc = ((size_t)b * HW + x0 + r) * CIN + c0 + cg;
      size_t wsrc = ((size_t)(oh * 128 + r)) * CIN + c0 + cg;
      unsigned lb = (unsigned)((i * 256 + wave * 64) << 4);
      gll16(&xt_hi[xsrc], &L[0][lb]);
      gll16(&xt_lo[xsrc], &L[1][lb]);
      gll16(&w_hi[wsrc],  &L[2][lb]);
      gll16(&w_lo[wsrc],  &L[3][lb]);
    }
    __syncthreads();
#pragma unroll
    for (int st = 0; st < 2; ++st) {
      int cb = st * 4 + (lane >> 4);
      v8bf ah0 = lds_frag128(L[0], wave * 32 + (lane & 15), cb);
      v8bf ah1 = lds_frag128(L[0], wave * 32 + 16 + (lane & 15), cb);
      v8bf al0 = lds_frag128(L[1], wave * 32 + (lane & 15), cb);
      v8bf al1 = lds_frag128(L[1], wave * 32 + 16 + (lane & 15), cb);
#pragma unroll
      for (int of = 0; of < 8; ++of) {
        v8bf bh = lds_frag128(L[2], of * 16 + (lane & 15), cb);
        v8bf bl = lds_frag128(L[3], of * 16 + (lane & 15), cb);
        acc[0][of] = mfma16(ah0, bh, acc[0][of]);
        acc[0][of] = mfma16(ah0, bl, acc[0][of]);
        acc[0][of] = mfma16(al0, bh, acc[0][of]);
        acc[1][of] = mfma16(ah1, bh, acc[1][of]);
        acc[1][of] = mfma16(ah1, bl, acc[1][of]);
        acc[1][of] = mfma16(al1, bh, acc[1][of]);
      }
    }
    __syncthreads();
  }

  // epilogue: bias + f16 -> LDS transpose -> coalesced store
  ushort_t* Th = (ushort_t*)&L[0][0];  // [128][128]
#pragma unroll
  for (int xf = 0; xf < 2; ++xf)
#pragma unroll
    for (int of = 0; of < 8; ++of)
#pragma unroll
      for (int r = 0; r < 4; ++r) {
        int x_loc = wave * 32 + xf * 16 + (lane >> 4) * 4 + r;
        int o_loc = of * 16 + (lane & 15);
        Th[x_loc * 128 + o_loc] = f2h(acc[xf][of][r] + bias_of[of]);
      }
  __syncthreads();
  {
    int row = t >> 1, half = t & 1;
    size_t off = ((size_t)b * HW + x0 + row) * CO + oh * 128 + half * 64;
#pragma unroll
    for (int j = 0; j < 8; ++j)
      *(uint4*)&proj_h[off + j * 8] =
          *(const uint4*)&Th[row * 128 + half * 64 + j * 8];
  }
}

// ===========================================================================
// pem [b][c][y] fp32 -> pem_t_h[b][y][c] f16 (transposed)  +  pem_h[b][c][y] f16
// ===========================================================================
__global__ __launch_bounds__(256) void k_tr_pem(
    const float* __restrict__ pem,
    ushort_t* __restrict__ pem_t_h, ushort_t* __restrict__ pem_h) {
  __shared__ float T[64][65];  // [c][y]
  const int y0 = blockIdx.x * 64;
  const int c0 = blockIdx.y * 64;
  const int b  = blockIdx.z;
  const int t  = threadIdx.x;
  const int cl = t >> 4;
  const int y4 = (t & 15) * 4;
#pragma unroll
  for (int r = 0; r < 4; ++r) {
    int c = c0 + r * 16 + cl;
    size_t off = ((size_t)b * CO + c) * HW + y0 + y4;
    float4 v = *(const float4*)&pem[off];
    ushort4 h;
    h.x = f2h(v.x); h.y = f2h(v.y); h.z = f2h(v.z); h.w = f2h(v.w);
    *(ushort4*)&pem_h[off] = h;
    T[r * 16 + cl][y4 + 0] = v.x;
    T[r * 16 + cl][y4 + 1] = v.y;
    T[r * 16 + cl][y4 + 2] = v.z;
    T[r * 16 + cl][y4 + 3] = v.w;
  }
  __syncthreads();
  {
    int yl = t >> 2;
    int cs = (t & 3) * 16;
    u16x8 h0, h1;
#pragma unroll
    for (int j = 0; j < 8; ++j) h0[j] = f2h(T[cs + j][yl]);
#pragma unroll
    for (int j = 0; j < 8; ++j) h1[j] = f2h(T[cs + 8 + j][yl]);
    size_t ro = ((size_t)b * HW + y0 + yl) * CO + c0 + cs;
    *(u16x8*)&pem_t_h[ro]     = h0;
    *(u16x8*)&pem_t_h[ro + 8] = h1;
  }
}

// ===========================================================================
// Pass 1: stats + E' materialization, y-segmented. Single-term f16 MFMA.
// grid: nb*32(xt)*4(seg). Block 256 thr, x-tile 128, A (proj f16) in regs.
// Defer-max (THR=8). E' flushed coalesced -> Ep[bl*32+xt][y][128] f16.
// ===========================================================================
__global__ __launch_bounds__(256, 3) void k_pass1(
    const ushort_t* __restrict__ proj_h, const ushort_t* __restrict__ pem_t_h,
    _Float16* __restrict__ Ep, float* __restrict__ m_snap,
    float* __restrict__ m_seg, float* __restrict__ d_seg,
    int nb, int b_base) {
  __shared__ __align__(16) unsigned char pbuf[2][32 * 512];  // 32 KB
  __shared__ __align__(16) unsigned char Etr[2][32 * 256];   // 16 KB
  const int id = blockIdx.x;
  const int brel = id % nb;
  const int b = b_base + brel;
  const int rest = id / nb;
  const int xt = rest & 31;
  const int seg = rest >> 5;
  const int x0 = xt * 128;
  const int t = threadIdx.x;
  const int lane = t & 63, wave = t >> 6;
  const int xw = x0 + wave * 32;

  // A fragments resident in registers (proj f16, K=256): 64 VGPR
  v8h Ah[2][8];
#pragma unroll
  for (int xf = 0; xf < 2; ++xf) {
    const size_t ro =
        ((size_t)b * HW + xw + xf * 16 + (lane & 15)) * CO + (lane >> 4) * 8;
#pragma unroll
    for (int st = 0; st < 8; ++st)
      Ah[xf][st] = __builtin_bit_cast(v8h, *(const uint4*)&proj_h[ro + st * 32]);
  }

  float m[2][4], d[2][4];
#pragma unroll
  for (int xf = 0; xf < 2; ++xf)
#pragma unroll
    for (int r = 0; r < 4; ++r) { m[xf][r] = -3.0e38f; d[xf][r] = 0.f; }

  auto stage = [&](int bufi, int tt) {
    const int yy0 = tt * 32;
#pragma unroll
    for (int i = 0; i < 4; ++i) {
      int G = i * 256 + t;
      int r = G >> 5, sl = G & 31;
      size_t so = ((size_t)b * HW + yy0 + r) * CO + ((sl ^ (r & 7)) << 3);
      unsigned lb = (unsigned)((i * 256 + wave * 64) << 4);
      gll16(&pem_t_h[so], &pbuf[bufi][lb]);
    }
  };

  const int tt0 = seg * SEGC;
  stage(0, tt0);
  __syncthreads();

  for (int tc = 0; tc < SEGC; ++tc) {
    const int tt = tt0 + tc;
    if (tc + 1 < SEGC) stage((tc + 1) & 1, tt + 1);

    const unsigned char* bp = pbuf[tc & 1];
    v4f acc[2][2];
#pragma unroll
    for (int xf = 0; xf < 2; ++xf)
#pragma unroll
      for (int yc = 0; yc < 2; ++yc) acc[xf][yc] = (v4f){0.f, 0.f, 0.f, 0.f};

#pragma unroll
    for (int st = 0; st < 8; ++st) {
#pragma unroll
      for (int yc = 0; yc < 2; ++yc) {
        int row = yc * 16 + (lane & 15);
        int cb  = st * 4 + (lane >> 4);
        v8h bh = lds_frag_h512(bp, row, cb);
        acc[0][yc] = mfma16h(Ah[0][st], bh, acc[0][yc]);
        acc[1][yc] = mfma16h(Ah[1][st], bh, acc[1][yc]);
      }
    }

    // ---- defer-max stats + E' ----
#pragma unroll
    for (int xf = 0; xf < 2; ++xf) {
      float mx8 = fmaxf(fmaxf(fmaxf(acc[xf][0][0], acc[xf][0][1]),
                              fmaxf(acc[xf][0][2], acc[xf][0][3])),
                        fmaxf(fmaxf(acc[xf][1][0], acc[xf][1][1]),
                              fmaxf(acc[xf][1][2], acc[xf][1][3])));
      float minm = fminf(fminf(m[xf][0], m[xf][1]), fminf(m[xf][2], m[xf][3]));
      if (__any(mx8 > minm + 8.0f)) {
#pragma unroll
        for (int r = 0; r < 4; ++r) {
          float rm = fmaxf(acc[xf][0][r], acc[xf][1][r]);
          rm = fmaxf(rm, __shfl_xor(rm, 1));
          rm = fmaxf(rm, __shfl_xor(rm, 2));
          rm = fmaxf(rm, __shfl_xor(rm, 4));
          rm = fmaxf(rm, __shfl_xor(rm, 8));
          float mn = fmaxf(m[xf][r], rm);
          d[xf][r] *= __expf(m[xf][r] - mn);
          m[xf][r] = mn;
        }
      }
      v4h p0, p1;
#pragma unroll
      for (int r = 0; r < 4; ++r) {
        float e0 = __expf(acc[xf][0][r] - m[xf][r]);
        float e1 = __expf(acc[xf][1][r] - m[xf][r]);
        d[xf][r] += e0 + e1;
        p0[r] = (_Float16)e0;
        p1[r] = (_Float16)e1;
      }
      {
        int gx = (wave * 32 + xf * 16 + (lane >> 4) * 4) >> 3;
        int half = (lane >> 4) & 1;
        int y0l = lane & 15, y1l = 16 + (lane & 15);
        *(uint2*)&Etr[tc & 1][y0l * 256 + ((gx ^ (y0l & 15)) << 4) + half * 8] =
            __builtin_bit_cast(uint2, p0);
        *(uint2*)&Etr[tc & 1][y1l * 256 + ((gx ^ (y1l & 15)) << 4) + half * 8] =
            __builtin_bit_cast(uint2, p1);
      }
      if ((lane & 15) == 0) {
        *(float4*)&m_snap[((size_t)b * NCHUNK + tt) * HW + xw + xf * 16 +
                          (lane >> 4) * 4] =
            make_float4(m[xf][0], m[xf][1], m[xf][2], m[xf][3]);
      }
    }
    __syncthreads();  // Etr ready; gll16 drained; pbuf[cur] reads done
    // ---- flush Etr -> Ep (coalesced 32B per thread) ----
    {
      int yr = t >> 3;
      int g0 = (t & 7) * 2, g1 = g0 + 1;
      uint4 v0 = *(uint4*)&Etr[tc & 1][yr * 256 + ((g0 ^ (yr & 15)) << 4)];
      uint4 v1 = *(uint4*)&Etr[tc & 1][yr * 256 + ((g1 ^ (yr & 15)) << 4)];
      size_t go = (((size_t)(brel * 32 + xt)) * HW + (size_t)tt * 32 + yr) * 128;
      *(uint4*)&Ep[go + g0 * 8] = v0;
      *(uint4*)&Ep[go + g1 * 8] = v1;
    }
  }

  // ---- segment (m, d) out ----
#pragma unroll
  for (int xf = 0; xf < 2; ++xf) {
    float dv[4];
#pragma unroll
    for (int r = 0; r < 4; ++r) {
      float v = d[xf][r];
      v += __shfl_xor(v, 1);
      v += __shfl_xor(v, 2);
      v += __shfl_xor(v, 4);
      v += __shfl_xor(v, 8);
      dv[r] = v;
    }
    if ((lane & 15) == 0) {
      size_t o = ((size_t)(b * NSEG + seg)) * HW + xw + xf * 16 + (lane >> 4) * 4;
      *(float4*)&m_seg[o] = make_float4(m[xf][0], m[xf][1], m[xf][2], m[xf][3]);
      *(float4*)&d_seg[o] = make_float4(dv[0], dv[1], dv[2], dv[3]);
    }
  }
}

// ===========================================================================
// Merge segments -> Mx, Dinv
// ===========================================================================
__global__ __launch_bounds__(256) void k_red(
    const float* __restrict__ m_seg, const float* __restrict__ d_seg,
    float* __restrict__ Mx, float* __restrict__ Dinv, int b_base) {
  int idx = blockIdx.x * 256 + threadIdx.x;
  int b = b_base + (idx >> 12);
  int xx = idx & 4095;
  float ms[NSEG], ds[NSEG];
  float mm = -3.0e38f;
#pragma unroll
  for (int s = 0; s < NSEG; ++s) {
    ms[s] = m_seg[((size_t)(b * NSEG + s)) * HW + xx];
    ds[s] = d_seg[((size_t)(b * NSEG + s)) * HW + xx];
    mm = fmaxf(mm, ms[s]);
  }
  float dd = 0.f;
#pragma unroll
  for (int s = 0; s < NSEG; ++s) dd += ds[s] * __expf(ms[s] - mm);
  Mx[(size_t)b * HW + xx]   = mm;
  Dinv[(size_t)b * HW + xx] = 1.0f / dd;
}

// ===========================================================================
// Pass 2: out[b,k,y] = sum_x pem[k,x] * s(tt(y),x) * E'[x,y]  (f16 MFMA)
// ===========================================================================
__global__ __launch_bounds__(256, 2) void k_pass2(
    const _Float16* __restrict__ Ep, const ushort_t* __restrict__ pem_h_u,
    const float* __restrict__ m_snap, const float* __restrict__ Mx,
    const float* __restrict__ Dinv, float* __restrict__ out,
    int nb, int b_base) {
  __shared__ __align__(16) unsigned char pml[128 * 256];   // 32 KB
  __shared__ __align__(16) unsigned char el[2][64 * 256];  // 32 KB
  __shared__ __align__(16) _Float16 slds[2][256];
  const int id = blockIdx.x;
  const int brel = id % nb;
  const int b = b_base + brel;
  const int rest = id / nb;
  const int kh = rest & 1;
  const int yt = rest >> 1;
  const int y0 = yt * 64;
  const int t = threadIdx.x;
  const int lane = t & 63, wave = t >> 6;
  const _Float16* pem_h = (const _Float16*)pem_h_u;

  v4f oacc[2][4];
#pragma unroll
  for (int kf = 0; kf < 2; ++kf)
#pragma unroll
    for (int yf = 0; yf < 4; ++yf) oacc[kf][yf] = (v4f){0.f, 0.f, 0.f, 0.f};

  auto stage_pml = [&](int xt) {
#pragma unroll
    for (int i = 0; i < 8; ++i) {
      int G = i * 256 + t;
      int r = G >> 4, sl = G & 15;
      size_t so = ((size_t)b * CO + kh * 128 + r) * HW + xt * 128 +
                  ((sl ^ (r & 15)) << 3);
      gll16(&pem_h[so], &pml[(unsigned)((i * 256 + wave * 64) << 4)]);
    }
  };
  auto load_el = [&](int xt, uint4* ev) {
    const size_t slab = ((size_t)(brel * 32 + xt)) * HW * 128;
#pragma unroll
    for (int i = 0; i < 4; ++i) {
      int G = i * 256 + t;
      ev[i] = *(const uint4*)&Ep[slab + (size_t)(y0 + (G >> 4)) * 128 +
                                 (G & 15) * 8];
    }
  };
  auto comp_s = [&](int bufi, int xt) {
    int ttrel = t >> 7, xr = t & 127;
    int ttg = (y0 >> 5) + ttrel;
    size_t xg = (size_t)xt * 128 + xr;
    float ms = m_snap[((size_t)b * NCHUNK + ttg) * HW + xg];
    float s = __expf(ms - Mx[(size_t)b * HW + xg]) * Dinv[(size_t)b * HW + xg];
    slds[bufi][ttrel * 128 + xr] = (_Float16)s;
  };
  auto write_el = [&](int bufi, const uint4* ev) {
#pragma unroll
    for (int i = 0; i < 4; ++i) {
      int G = i * 256 + t;
      int yl = G >> 4, sl = G & 15;
      v8h e = __builtin_bit_cast(v8h, ev[i]);
      v8h s = *(const v8h*)&slds[bufi][(yl >> 5) * 128 + sl * 8];
      e = e * s;
      *(uint4*)&el[bufi][yl * 256 + ((sl ^ (yl & 15)) << 4)] =
          __builtin_bit_cast(uint4, e);
    }
  };

  uint4 ev[4];
  // prologue
  comp_s(0, 0);
  load_el(0, ev);
  stage_pml(0);
  __syncthreads();          // slds[0] visible, pml(0) ready
  write_el(0, ev);
  comp_s(1, 1);
  __syncthreads();          // el[0], slds[1] visible

  for (int xt = 0; xt < 32; ++xt) {
    const int cur = xt & 1, nxt = cur ^ 1;
    if (xt + 1 < 32) load_el(xt + 1, ev);
    // ---- MFMA ----
#pragma unroll
    for (int st = 0; st < 4; ++st) {
      int cb = st * 4 + (lane >> 4);
      v8h af0 = lds_frag_h16(pml, wave * 32 + (lane & 15), cb);
      v8h af1 = lds_frag_h16(pml, wave * 32 + 16 + (lane & 15), cb);
      v8h bf0 = lds_frag_h16(el[cur], 0 + (lane & 15), cb);
      v8h bf1 = lds_frag_h16(el[cur], 16 + (lane & 15), cb);
      v8h bf2 = lds_frag_h16(el[cur], 32 + (lane & 15), cb);
      v8h bf3 = lds_frag_h16(el[cur], 48 + (lane & 15), cb);
      oacc[0][0] = mfma16h(af0, bf0, oacc[0][0]);
      oacc[0][1] = mfma16h(af0, bf1, oacc[0][1]);
      oacc[0][2] = mfma16h(af0, bf2, oacc[0][2]);
      oacc[0][3] = mfma16h(af0, bf3, oacc[0][3]);
      oacc[1][0] = mfma16h(af1, bf0, oacc[1][0]);
      oacc[1][1] = mfma16h(af1, bf1, oacc[1][1]);
      oacc[1][2] = mfma16h(af1, bf2, oacc[1][2]);
      oacc[1][3] = mfma16h(af1, bf3, oacc[1][3]);
    }
    __syncthreads();        // pml/el[cur] reads done by all waves
    if (xt + 1 < 32) {
      stage_pml(xt + 1);
      write_el(nxt, ev);
      if (xt + 2 < 32) comp_s(cur, xt + 2);
    }
    __syncthreads();        // gll16 drained; el[nxt]/slds visible
  }

#pragma unroll
  for (int kf = 0; kf < 2; ++kf)
#pragma unroll
    for (int yf = 0; yf < 4; ++yf)
#pragma unroll
      for (int r = 0; r < 4; ++r) {
        int k = kh * 128 + wave * 32 + kf * 16 + (lane >> 4) * 4 + r;
        int y = y0 + yf * 16 + (lane & 15);
        out[((size_t)b * CO + k) * HW + y] = oacc[kf][yf][r];
      }
}

// ===========================================================================
// fp32 fallback path (used only if ws is too small)
// ===========================================================================
__global__ __launch_bounds__(256) void k_proj(
    const float* __restrict__ x, const float* __restrict__ W,
    const float* __restrict__ bias, float* __restrict__ proj) {
  __shared__ float As[KT][68];
  __shared__ float Bs[KT][68];
  const int i0 = blockIdx.x * 64;
  const int o0 = blockIdx.y * 64;
  const int b  = blockIdx.z;
  const int t  = threadIdx.x;
  const int tx = t & 15, ty = t >> 4;
  const float* xb = x + (size_t)b * CIN * HW;
  float acc[4][4] = {};
  for (int c0 = 0; c0 < CIN; c0 += KT) {
#pragma unroll
    for (int l = 0; l < 8; ++l) {
      int idx = t + l * 256;
      int o = idx >> 5;
      int c = idx & 31;
      As[c][o] = W[(size_t)(o0 + o) * CIN + c0 + c];
    }
#pragma unroll
    for (int l = 0; l < 2; ++l) {
      int idx4 = t + l * 256;
      int c = idx4 >> 4;
      int i4 = idx4 & 15;
      *(float4*)&Bs[c][i4 * 4] =
          *(const float4*)&xb[(size_t)(c0 + c) * HW + i0 + i4 * 4];
    }
    __syncthreads();
#pragma unroll
    for (int c = 0; c < KT; ++c) {
      float4 a  = *(const float4*)&As[c][tx * 4];
      float4 bv = *(const float4*)&Bs[c][ty * 4];
      float av[4] = {a.x, a.y, a.z, a.w};
      float bb[4] = {bv.x, bv.y, bv.z, bv.w};
#pragma unroll
      for (int u = 0; u < 4; ++u)
#pragma unroll
        for (int v = 0; v < 4; ++v) acc[u][v] += av[u] * bb[v];
    }
    __syncthreads();
  }
  float* pbout = proj + (size_t)b * CO * HW;
#pragma unroll
  for (int u = 0; u < 4; ++u) {
    int o = o0 + tx * 4 + u;
    float bsv = bias[o];
    float4 r;
    r.x = acc[u][0] + bsv; r.y = acc[u][1] + bsv;
    r.z = acc[u][2] + bsv; r.w = acc[u][3] + bsv;
    *(float4*)&pbout[(size_t)o * HW + i0 + ty * 4] = r;
  }
}

__global__ __launch_bounds__(256) void k_stats(
    const float* __restrict__ proj, const float* __restrict__ pem,
    float* __restrict__ Mx, float* __restrict__ Dinv) {
  __shared__ float As[KT][68];
  __shared__ float Bs[KT][68];
  __shared__ float MsS[64][17];
  __shared__ float DsS[64][17];
  const int x0 = blockIdx.x * 64;
  const int b  = blockIdx.y;
  const int t  = threadIdx.x;
  const int tx = t & 15, ty = t >> 4;
  const float* pj = proj + (size_t)b * CO * HW;
  const float* pe = pem + (size_t)b * CO * HW;
  float m[4], d[4];
#pragma unroll
  for (int u = 0; u < 4; ++u) { m[u] = -3.0e38f; d[u] = 0.f; }
  for (int y0 = 0; y0 < HW; y0 += 64) {
    float s[4][4] = {};
    for (int c0 = 0; c0 < CO; c0 += KT) {
#pragma unroll
      for (int l = 0; l < 2; ++l) {
        int idx4 = t + l * 256;
        int c = idx4 >> 4, w4 = idx4 & 15;
        *(float4*)&As[c][w4 * 4] =
            *(const float4*)&pj[(size_t)(c0 + c) * HW + x0 + w4 * 4];
        *(float4*)&Bs[c][w4 * 4] =
            *(const float4*)&pe[(size_t)(c0 + c) * HW + y0 + w4 * 4];
      }
      __syncthreads();
#pragma unroll
      for (int c = 0; c < KT; ++c) {
        float4 a  = *(const float4*)&As[c][tx * 4];
        float4 bv = *(const float4*)&Bs[c][ty * 4];
        float av[4] = {a.x, a.y, a.z, a.w};
        float bb[4] = {bv.x, bv.y, bv.z, bv.w};
#pragma unroll
        for (int u = 0; u < 4; ++u)
#pragma unroll
          for (int v = 0; v < 4; ++v) s[u][v] += av[u] * bb[v];
      }
      __syncthreads();
    }
#pragma unroll
    for (int u = 0; u < 4; ++u) {
      float mv = fmaxf(fmaxf(s[u][0], s[u][1]), fmaxf(s[u][2], s[u][3]));
      if (mv > m[u]) { d[u] *= __expf(m[u] - mv); m[u] = mv; }
      d[u] += __expf(s[u][0] - m[u]) + __expf(s[u][1] - m[u]) +
              __expf(s[u][2] - m[u]) + __expf(s[u][3] - m[u]);
    }
  }
#pragma unroll
  for (int u = 0; u < 4; ++u) { MsS[tx * 4 + u][ty] = m[u]; DsS[tx * 4 + u][ty] = d[u]; }
  __syncthreads();
  if (t < 64) {
    float mm = -3.0e38f;
#pragma unroll
    for (int i = 0; i < 16; ++i) mm = fmaxf(mm, MsS[t][i]);
    float dd = 0.f;
#pragma unroll
    for (int i = 0; i < 16; ++i) dd += DsS[t][i] * __expf(MsS[t][i] - mm);
    Mx[(size_t)b * HW + x0 + t]   = mm;
    Dinv[(size_t)b * HW + x0 + t] = 1.0f / dd;
  }
}

__global__ __launch_bounds__(256) void k_out(
    const float* __restrict__ proj, const float* __restrict__ pem,
    const float* __restrict__ Mx, const float* __restrict__ Dinv,
    float* __restrict__ out) {
  __shared__ float As[KT][68];
  __shared__ float Bs[KT][68];
  __shared__ float E[64][68];
  const int y0 = blockIdx.x * 64;
  const int b  = blockIdx.y;
  const int t  = threadIdx.x;
  const int tx = t & 15, ty = t >> 4;
  const int kg = t >> 3, yg = t & 7;
  const float* pj = proj + (size_t)b * CO * HW;
  const float* pe = pem + (size_t)b * CO * HW;
  const float* Mb = Mx + (size_t)b * HW;
  const float* Db = Dinv + (size_t)b * HW;
  float acc[8][8] = {};
  for (int x0 = 0; x0 < HW; x0 += 64) {
    float s[4][4] = {};
    for (int c0 = 0; c0 < CO; c0 += KT) {
#pragma unroll
      for (int l = 0; l < 2; ++l) {
        int idx4 = t + l * 256;
        int c = idx4 >> 4, w4 = idx4 & 15;
        *(float4*)&As[c][w4 * 4] =
            *(const float4*)&pj[(size_t)(c0 + c) * HW + x0 + w4 * 4];
        *(float4*)&Bs[c][w4 * 4] =
            *(const float4*)&pe[(size_t)(c0 + c) * HW + y0 + w4 * 4];
      }
      __syncthreads();
#pragma unroll
      for (int c = 0; c < KT; ++c) {
        float4 a  = *(const float4*)&As[c][tx * 4];
        float4 bv = *(const float4*)&Bs[c][ty * 4];
        float av[4] = {a.x, a.y, a.z, a.w};
        float bb[4] = {bv.x, bv.y, bv.z, bv.w};
#pragma unroll
        for (int u = 0; u < 4; ++u)
#pragma unroll
          for (int v = 0; v < 4; ++v) s[u][v] += av[u] * bb[v];
      }
      __syncthreads();
    }
#pragma unroll
    for (int u = 0; u < 4; ++u) {
      int xr = x0 + tx * 4 + u;
      float mm = Mb[xr];
      float di = Db[xr];
      E[tx * 4 + u][ty * 4 + 0] = __expf(s[u][0] - mm) * di;
      E[tx * 4 + u][ty * 4 + 1] = __expf(s[u][1] - mm) * di;
      E[tx * 4 + u][ty * 4 + 2] = __expf(s[u][2] - mm) * di;
      E[tx * 4 + u][ty * 4 + 3] = __expf(s[u][3] - mm) * di;
    }
    __syncthreads();
    for (int xi = 0; xi < 64; xi += 4) {
      float4 p[8];
#pragma unroll
      for (int u = 0; u < 8; ++u)
        p[u] = *(const float4*)&pe[(size_t)(kg * 8 + u) * HW + x0 + xi];
#pragma unroll
      for (int j = 0; j < 4; ++j) {
        float4 e0 = *(const float4*)&E[xi + j][yg * 8];
        float4 e1 = *(const float4*)&E[xi + j][yg * 8 + 4];
        float evv[8] = {e0.x, e0.y, e0.z, e0.w, e1.x, e1.y, e1.z, e1.w};
#pragma unroll
        for (int u = 0; u < 8; ++u) {
          float a = (j == 0) ? p[u].x : (j == 1) ? p[u].y : (j == 2) ? p[u].z : p[u].w;
#pragma unroll
          for (int v = 0; v < 8; ++v) acc[u][v] += a * evv[v];
        }
      }
    }
    __syncthreads();
  }
#pragma unroll
  for (int u = 0; u < 8; ++u) {
    int k = kg * 8 + u;
    float4 r0, r1;
    r0.x = acc[u][0]; r0.y = acc[u][1]; r0.z = acc[u][2]; r0.w = acc[u][3];
    r1.x = acc[u][4]; r1.y = acc[u][5]; r1.z = acc[u][6]; r1.w = acc[u][7];
    float* ob = out + ((size_t)b * CO + k) * HW + y0 + yg * 8;
    *(float4*)&ob[0] = r0;
    *(float4*)&ob[4] = r1;
  }
}

// ===========================================================================
extern "C" void kernel_launch(void* const* d_in, const int* in_sizes, int n_in,
                              void* d_out, int out_size, void* d_ws, size_t ws_size,
                              hipStream_t stream) {
  const float* x    = (const float*)d_in[0];
  const float* pem  = (const float*)d_in[1];
  const float* W    = (const float*)d_in[2];
  const float* bias = (const float*)d_in[3];
  float* out = (float*)d_out;

  const size_t NS   = (size_t)BATCH * HW * CO;       // 8.39M
  const size_t NS2  = (size_t)BATCH * HW * CIN;      // 16.78M
  const size_t HWB  = (size_t)BATCH * HW;            // 32768
  const size_t SNAP = (size_t)BATCH * NCHUNK * HW;   // 4.19M
  const size_t SEGN = (size_t)BATCH * NSEG * HW;     // 131072

  unsigned char* basep = (unsigned char*)d_ws;
  ushort_t* proj_h   = (ushort_t*)basep;
  ushort_t* pem_t_h  = proj_h + NS;
  ushort_t* pem_h    = pem_t_h + NS;
  float*    Mx       = (float*)(pem_h + NS);
  float*    Dinv     = Mx + HWB;
  float*    m_seg    = Dinv + HWB;
  float*    d_seg    = m_seg + SEGN;
  float*    m_snap   = d_seg + SEGN;
  _Float16* Ep       = (_Float16*)(m_snap + SNAP);

  // x_t / W-split live inside the Ep region (consumed before pass1 writes Ep)
  ushort_t* xt_hi = (ushort_t*)Ep;
  ushort_t* xt_lo = xt_hi + NS2;
  ushort_t* w_hi  = xt_lo + NS2;
  ushort_t* w_lo  = w_hi + (size_t)CO * CIN;

  const size_t base_need = 3 * NS * 2 + 2 * HWB * 4 + 2 * SEGN * 4 + SNAP * 4;
  const size_t e_full    = (size_t)BATCH * HW * HW * 2;   // 268.4 MB

  int rounds, nb;
  if (ws_size >= base_need + e_full)          { rounds = 1; nb = 8; }
  else if (ws_size >= base_need + e_full / 2) { rounds = 2; nb = 4; }
  else {
    // fp32 fallback
    float* proj = (float*)d_ws;
    float* Mx2  = proj + NS;
    float* Di2  = Mx2 + HWB;
    const size_t need = (NS + 2 * HWB) * sizeof(float);
    if (ws_size < need) return;
    k_proj <<<dim3(HW / 64, CO / 64, BATCH), 256, 0, stream>>>(x, W, bias, proj);
    k_stats<<<dim3(HW / 64, BATCH),          256, 0, stream>>>(proj, pem, Mx2, Di2);
    k_out  <<<dim3(HW / 64, BATCH),          256, 0, stream>>>(proj, pem, Mx2, Di2, out);
    return;
  }

  k_w_split<<<64, 256, 0, stream>>>(W, w_hi, w_lo);
  k_tr_x<<<dim3(HW / 64, CIN / 64, BATCH), 256, 0, stream>>>(x, xt_hi, xt_lo);
  k_proj_mfma<<<512, 256, 0, stream>>>(xt_hi, xt_lo, w_hi, w_lo, bias, proj_h);
  k_tr_pem<<<dim3(HW / 64, CO / 64, BATCH), 256, 0, stream>>>(
      pem, pem_t_h, pem_h);

  for (int rd = 0; rd < rounds; ++rd) {
    int b_base = rd * nb;
    k_pass1<<<nb * 128, 256, 0, stream>>>(proj_h, pem_t_h,
                                          Ep, m_snap, m_seg, d_seg, nb, b_base);
    k_red<<<nb * 16, 256, 0, stream>>>(m_seg, d_seg, Mx, Dinv, b_base);
    k_pass2<<<nb * 128, 256, 0, stream>>>(Ep, pem_h, m_snap,
                                          Mx, Dinv, out, nb, b_base);
  }
}